// Round 1
// baseline (1282.618 us; speedup 1.0000x reference)
//
#include <hip/hip_runtime.h>
#include <hip/hip_bf16.h>
#include <math.h>

// Problem constants (B=8, S=2048, D=512, H=8, Dh=64, u = 5*ceil(ln(2048)) = 40)
#define NB 8
#define NS 2048
#define ND 512
#define NH 8
#define DHD 64
#define NU 40
#define NBH 64  // NB*NH

// ---- monotone float->uint mapping for atomic max over floats (any sign) ----
__device__ __forceinline__ unsigned fmap(float f) {
  unsigned u = __float_as_uint(f);
  return (u & 0x80000000u) ? ~u : (u | 0x80000000u);
}
__device__ __forceinline__ float finv(unsigned u) {
  return (u & 0x80000000u) ? __uint_as_float(u ^ 0x80000000u) : __uint_as_float(~u);
}

// ---------------------------------------------------------------------------
// Generic fp32 GEMM: C[16384x512] = A[16384x512] @ W[512x512] + bias
// BM=BN=128, BK=16, 256 threads, 8x8 micro-tile.
// SPLIT=1: write head-split layout Q[bh][s][dh]; SPLIT=0: plain row-major.
// ---------------------------------------------------------------------------
template <int SPLIT>
__global__ __launch_bounds__(256) void gemm128(const float* __restrict__ A,
                                               const float* __restrict__ W,
                                               const float* __restrict__ bias,
                                               float* __restrict__ C) {
  __shared__ float As[16][132];
  __shared__ float Bs[16][132];
  const int tid = threadIdx.x;
  const int bm = blockIdx.x, bn = blockIdx.y;
  const int tx = tid & 15, ty = tid >> 4;

  float acc[8][8];
#pragma unroll
  for (int i = 0; i < 8; ++i)
#pragma unroll
    for (int j = 0; j < 8; ++j) acc[i][j] = 0.f;

  const int arow = tid >> 2;          // 0..63
  const int acg = (tid & 3) << 2;     // 0,4,8,12

  for (int kt = 0; kt < 512; kt += 16) {
#pragma unroll
    for (int p = 0; p < 2; ++p) {
      // A tile: 128 rows x 16 cols
      int r = arow + (p << 6);
      const float4 a4 = *(const float4*)(A + (size_t)(bm * 128 + r) * 512 + kt + acg);
      As[acg + 0][r] = a4.x; As[acg + 1][r] = a4.y;
      As[acg + 2][r] = a4.z; As[acg + 3][r] = a4.w;
      // W tile: 16 rows x 128 cols
      int wr = (tid >> 5) + (p << 3);     // 0..15
      int wc = (tid & 31) << 2;           // 0..124
      *(float4*)&Bs[wr][wc] = *(const float4*)(W + (size_t)(kt + wr) * 512 + bn * 128 + wc);
    }
    __syncthreads();
#pragma unroll
    for (int kk = 0; kk < 16; ++kk) {
      float a[8], b[8];
      *(float4*)&a[0] = *(const float4*)&As[kk][ty * 8];
      *(float4*)&a[4] = *(const float4*)&As[kk][ty * 8 + 4];
      *(float4*)&b[0] = *(const float4*)&Bs[kk][tx * 8];
      *(float4*)&b[4] = *(const float4*)&Bs[kk][tx * 8 + 4];
#pragma unroll
      for (int i = 0; i < 8; ++i)
#pragma unroll
        for (int j = 0; j < 8; ++j) acc[i][j] = fmaf(a[i], b[j], acc[i][j]);
    }
    __syncthreads();
  }

#pragma unroll
  for (int i = 0; i < 8; ++i) {
    int m = bm * 128 + ty * 8 + i;
#pragma unroll
    for (int j = 0; j < 8; ++j) {
      int n = bn * 128 + tx * 8 + j;
      float v = acc[i][j] + bias[n];
      if (SPLIT) {
        int b = m >> 11, s = m & 2047, h = n >> 6, dh = n & 63;
        C[((size_t)((b << 3) + h) * 2048 + s) * 64 + dh] = v;
      } else {
        C[(size_t)m * 512 + n] = v;
      }
    }
  }
}

// ---------------------------------------------------------------------------
// Row-max of raw QK^T per (bh): Mmax[bh][q] = max_k sum_dh Q[q][dh]*K[k][dh]
// (scale by 1/8 applied later; max commutes with positive scale)
// ---------------------------------------------------------------------------
__global__ __launch_bounds__(256) void qk_rowmax(const float* __restrict__ Q,
                                                 const float* __restrict__ K,
                                                 unsigned* __restrict__ Mmax) {
  __shared__ float As[16][132];
  __shared__ float Bs[16][132];
  const int tid = threadIdx.x;
  const int bh = blockIdx.z;
  const float* Qb = Q + ((size_t)bh * 2048 + blockIdx.x * 128) * 64;
  const float* Kb = K + ((size_t)bh * 2048 + blockIdx.y * 128) * 64;
  const int tx = tid & 15, ty = tid >> 4;

  float acc[8][8];
#pragma unroll
  for (int i = 0; i < 8; ++i)
#pragma unroll
    for (int j = 0; j < 8; ++j) acc[i][j] = 0.f;

  for (int kt = 0; kt < 64; kt += 16) {
#pragma unroll
    for (int p = 0; p < 2; ++p) {
      int idx = tid + (p << 8);     // 0..511
      int r = idx >> 2;             // 0..127
      int cg = (idx & 3) << 2;
      const float4 a4 = *(const float4*)(Qb + (size_t)r * 64 + kt + cg);
      As[cg + 0][r] = a4.x; As[cg + 1][r] = a4.y;
      As[cg + 2][r] = a4.z; As[cg + 3][r] = a4.w;
      const float4 b4 = *(const float4*)(Kb + (size_t)r * 64 + kt + cg);
      Bs[cg + 0][r] = b4.x; Bs[cg + 1][r] = b4.y;
      Bs[cg + 2][r] = b4.z; Bs[cg + 3][r] = b4.w;
    }
    __syncthreads();
#pragma unroll
    for (int kk = 0; kk < 16; ++kk) {
      float a[8], b[8];
      *(float4*)&a[0] = *(const float4*)&As[kk][ty * 8];
      *(float4*)&a[4] = *(const float4*)&As[kk][ty * 8 + 4];
      *(float4*)&b[0] = *(const float4*)&Bs[kk][tx * 8];
      *(float4*)&b[4] = *(const float4*)&Bs[kk][tx * 8 + 4];
#pragma unroll
      for (int i = 0; i < 8; ++i)
#pragma unroll
        for (int j = 0; j < 8; ++j) acc[i][j] = fmaf(a[i], b[j], acc[i][j]);
    }
    __syncthreads();
  }

#pragma unroll
  for (int i = 0; i < 8; ++i) {
    float r = acc[i][0];
#pragma unroll
    for (int j = 1; j < 8; ++j) r = fmaxf(r, acc[i][j]);
#pragma unroll
    for (int off = 1; off < 16; off <<= 1) r = fmaxf(r, __shfl_xor(r, off, 64));
    if (tx == 0)
      atomicMax(&Mmax[(size_t)bh * 2048 + blockIdx.x * 128 + ty * 8 + i], fmap(r));
  }
}

// ---------------------------------------------------------------------------
// Column means of K and V per (bh): kbar/vbar[bh][dh]
// ---------------------------------------------------------------------------
__global__ __launch_bounds__(256) void colmeans(const float* __restrict__ K,
                                                const float* __restrict__ V,
                                                float* __restrict__ kbar,
                                                float* __restrict__ vbar) {
  const int bh = blockIdx.x;
  const int dd = threadIdx.x & 63, c = threadIdx.x >> 6;
  const float* Kb = K + (size_t)bh * 2048 * 64;
  const float* Vb = V + (size_t)bh * 2048 * 64;
  float sk = 0.f, sv = 0.f;
  for (int s = c * 512; s < (c + 1) * 512; ++s) {
    sk += Kb[(size_t)s * 64 + dd];
    sv += Vb[(size_t)s * 64 + dd];
  }
  __shared__ float rk[4][64], rv[4][64];
  rk[c][dd] = sk; rv[c][dd] = sv;
  __syncthreads();
  if (c == 0) {
    kbar[bh * 64 + dd] = (rk[0][dd] + rk[1][dd] + rk[2][dd] + rk[3][dd]) * (1.f / 2048.f);
    vbar[bh * 64 + dd] = (rv[0][dd] + rv[1][dd] + rv[2][dd] + rv[3][dd]) * (1.f / 2048.f);
  }
}

// ---------------------------------------------------------------------------
// M[bh][s] = (rawmax - q . kbar) / 8
// ---------------------------------------------------------------------------
__global__ void computeM(const float* __restrict__ Q, const unsigned* __restrict__ Mmax,
                         const float* __restrict__ kbar, float* __restrict__ Mval) {
  int idx = blockIdx.x * 256 + threadIdx.x;  // 0..131071 (= bh*2048+s)
  int bh = idx >> 11;
  const float* q = Q + (size_t)idx * 64;
  const float* kb = kbar + bh * 64;
  float dot = 0.f;
#pragma unroll
  for (int dd = 0; dd < 64; dd += 4) {
    float4 qv = *(const float4*)(q + dd);
    float4 kv = *(const float4*)(kb + dd);
    dot += qv.x * kv.x + qv.y * kv.y + qv.z * kv.z + qv.w * kv.w;
  }
  Mval[idx] = (finv(Mmax[idx]) - dot) * 0.125f;
}

// ---------------------------------------------------------------------------
// top-40 per (bh) by M, ties -> lower index (matches lax.top_k)
// ---------------------------------------------------------------------------
__global__ __launch_bounds__(256) void topk40(const float* __restrict__ Mval,
                                              int* __restrict__ tidx) {
  const int bh = blockIdx.x;
  __shared__ float v[2048];
  __shared__ float wv_[4];
  __shared__ int wi_[4];
  const int tid = threadIdx.x;
  for (int i = tid; i < 2048; i += 256) v[i] = Mval[(size_t)bh * 2048 + i];
  __syncthreads();
  for (int it = 0; it < NU; ++it) {
    float best = -INFINITY;
    int bi = 1 << 30;
    for (int i = tid; i < 2048; i += 256) {
      float x = v[i];
      if (x > best || (x == best && i < bi)) { best = x; bi = i; }
    }
    for (int off = 1; off < 64; off <<= 1) {
      float ov = __shfl_xor(best, off, 64);
      int oi = __shfl_xor(bi, off, 64);
      if (ov > best || (ov == best && oi < bi)) { best = ov; bi = oi; }
    }
    if ((tid & 63) == 0) { wv_[tid >> 6] = best; wi_[tid >> 6] = bi; }
    __syncthreads();
    if (tid == 0) {
      float bb = wv_[0]; int bbi = wi_[0];
      for (int w = 1; w < 4; ++w)
        if (wv_[w] > bb || (wv_[w] == bb && wi_[w] < bbi)) { bb = wv_[w]; bbi = wi_[w]; }
      tidx[bh * NU + it] = bbi;
      v[bbi] = -INFINITY;
    }
    __syncthreads();
  }
}

// ---------------------------------------------------------------------------
// Fill attn[b][s][h*64+dh] = vbar[bh][dh] for all rows (scatter overwrites top-u)
// ---------------------------------------------------------------------------
__global__ void fillmean(const float* __restrict__ vbar, float* __restrict__ attn) {
  const size_t n4 = (size_t)NB * NS * ND / 4;
  for (size_t i = (size_t)blockIdx.x * 256 + threadIdx.x; i < n4; i += (size_t)gridDim.x * 256) {
    size_t e = i << 2;
    int col = (int)(e & 511);
    int b = (int)(e >> 20);
    int h = col >> 6, dd = col & 63;
    *(float4*)(attn + e) = *(const float4*)(vbar + ((b << 3) + h) * 64 + dd);
  }
}

// ---------------------------------------------------------------------------
// Dense attention for the 40 selected queries of each (bh); online softmax.
// One block (256 thr) per bh; K/V streamed through LDS in 128-row tiles.
// ---------------------------------------------------------------------------
__global__ __launch_bounds__(256) void topattn(const float* __restrict__ Q,
                                               const float* __restrict__ K,
                                               const float* __restrict__ V,
                                               const int* __restrict__ topidx,
                                               float* __restrict__ attn) {
  __shared__ float qs[40][68];
  __shared__ float Kst[64][132];   // transposed: [dh][key]
  __shared__ float Vs[128][68];
  __shared__ float st[40][132];
  __shared__ float m_s[40], l_s[40], r_s[40];
  __shared__ int tix[40];
  const int tid = threadIdx.x;
  const int bh = blockIdx.x;
  const int bb = bh >> 3, hh = bh & 7;

  if (tid < 40) {
    tix[tid] = topidx[bh * NU + tid];
    m_s[tid] = -INFINITY;
    l_s[tid] = 0.f;
  }
  __syncthreads();
  for (int i = tid; i < 40 * 64; i += 256) {
    int q = i >> 6, dd = i & 63;
    qs[q][dd] = Q[((size_t)bh * 2048 + tix[q]) * 64 + dd];
  }
  const int tx = tid & 31, ty = tid >> 5;  // step1: 32 (key) x 8 (q-group)
  const int d = tid & 63, qb = tid >> 6;   // step3: 64 (dh) x 4 (q-phase)
  float acc[10];
#pragma unroll
  for (int j = 0; j < 10; ++j) acc[j] = 0.f;
  __syncthreads();

  for (int t = 0; t < 16; ++t) {
    // stage K (transposed) and V tiles: rows t*128 .. t*128+127
#pragma unroll
    for (int p = 0; p < 8; ++p) {
      int idx = tid + (p << 8);     // 0..2047
      int r = idx >> 4;             // 0..127
      int cg = (idx & 15) << 2;     // 0..60
      const float4 kv = *(const float4*)(K + ((size_t)bh * 2048 + t * 128 + r) * 64 + cg);
      Kst[cg + 0][r] = kv.x; Kst[cg + 1][r] = kv.y;
      Kst[cg + 2][r] = kv.z; Kst[cg + 3][r] = kv.w;
      *(float4*)&Vs[r][cg] = *(const float4*)(V + ((size_t)bh * 2048 + t * 128 + r) * 64 + cg);
    }
    __syncthreads();

    // step1: logits st[40][128], scaled by 1/8
    {
      float c5[5][4];
#pragma unroll
      for (int i = 0; i < 5; ++i)
#pragma unroll
        for (int j = 0; j < 4; ++j) c5[i][j] = 0.f;
      for (int dd = 0; dd < 64; ++dd) {
        const float4 b4 = *(const float4*)&Kst[dd][tx << 2];
#pragma unroll
        for (int i = 0; i < 5; ++i) {
          float a = qs[ty * 5 + i][dd];
          c5[i][0] = fmaf(a, b4.x, c5[i][0]);
          c5[i][1] = fmaf(a, b4.y, c5[i][1]);
          c5[i][2] = fmaf(a, b4.z, c5[i][2]);
          c5[i][3] = fmaf(a, b4.w, c5[i][3]);
        }
      }
#pragma unroll
      for (int i = 0; i < 5; ++i) {
        float4 o;
        o.x = c5[i][0] * 0.125f; o.y = c5[i][1] * 0.125f;
        o.z = c5[i][2] * 0.125f; o.w = c5[i][3] * 0.125f;
        *(float4*)&st[ty * 5 + i][tx << 2] = o;
      }
    }
    __syncthreads();

    // step2: online softmax bookkeeping (one thread per query)
    if (tid < 40) {
      float mold = m_s[tid];
      float tm = st[tid][0];
      for (int kk = 1; kk < 128; ++kk) tm = fmaxf(tm, st[tid][kk]);
      float mnew = fmaxf(mold, tm);
      float r = __expf(mold - mnew);   // 0 when mold = -inf
      float sum = 0.f;
      for (int kk = 0; kk < 128; ++kk) {
        float w = __expf(st[tid][kk] - mnew);
        st[tid][kk] = w;
        sum += w;
      }
      l_s[tid] = l_s[tid] * r + sum;
      m_s[tid] = mnew;
      r_s[tid] = r;
    }
    __syncthreads();

    // step3: PV accumulate
#pragma unroll
    for (int j = 0; j < 10; ++j) {
      int q = qb + (j << 2);
      float a = 0.f;
#pragma unroll
      for (int kk = 0; kk < 128; kk += 4) {
        float4 w = *(const float4*)&st[q][kk];
        a = fmaf(w.x, Vs[kk + 0][d], a);
        a = fmaf(w.y, Vs[kk + 1][d], a);
        a = fmaf(w.z, Vs[kk + 2][d], a);
        a = fmaf(w.w, Vs[kk + 3][d], a);
      }
      acc[j] = acc[j] * r_s[q] + a;
    }
    __syncthreads();
  }

#pragma unroll
  for (int j = 0; j < 10; ++j) {
    int q = qb + (j << 2);
    attn[((size_t)(bb * 2048) + tix[q]) * 512 + hh * 64 + d] = acc[j] / l_s[q];
  }
}

// ---------------------------------------------------------------------------
extern "C" void kernel_launch(void* const* d_in, const int* in_sizes, int n_in,
                              void* d_out, int out_size, void* d_ws, size_t ws_size,
                              hipStream_t stream) {
  (void)in_sizes; (void)n_in; (void)out_size; (void)ws_size;
  const float* x  = (const float*)d_in[0];
  const float* wq = (const float*)d_in[1];
  const float* bq = (const float*)d_in[2];
  const float* wk = (const float*)d_in[3];
  const float* bk = (const float*)d_in[4];
  const float* wv = (const float*)d_in[5];
  const float* bv = (const float*)d_in[6];
  const float* wo = (const float*)d_in[7];
  const float* bo = (const float*)d_in[8];
  float* out = (float*)d_out;

  const size_t NQKV = (size_t)NBH * NS * DHD;  // 8388608
  float* Qb   = (float*)d_ws;
  float* Kb   = Qb + NQKV;
  float* Vb   = Kb + NQKV;
  float* attn = Vb + NQKV;                     // [B][S][D], 8388608
  float* Mval = attn + NQKV;                   // 131072
  unsigned* Mmax = (unsigned*)(Mval + (size_t)NBH * NS);
  float* kbar = (float*)(Mmax + (size_t)NBH * NS);
  float* vbar = kbar + NBH * DHD;
  int* tidx   = (int*)(vbar + NBH * DHD);

  hipMemsetAsync(Mmax, 0, (size_t)NBH * NS * sizeof(unsigned), stream);

  dim3 g(128, 4);
  gemm128<1><<<g, 256, 0, stream>>>(x, wq, bq, Qb);
  gemm128<1><<<g, 256, 0, stream>>>(x, wk, bk, Kb);
  gemm128<1><<<g, 256, 0, stream>>>(x, wv, bv, Vb);
  colmeans<<<NBH, 256, 0, stream>>>(Kb, Vb, kbar, vbar);
  qk_rowmax<<<dim3(16, 16, NBH), 256, 0, stream>>>(Qb, Kb, Mmax);
  computeM<<<512, 256, 0, stream>>>(Qb, Mmax, kbar, Mval);
  topk40<<<NBH, 256, 0, stream>>>(Mval, tidx);
  fillmean<<<2048, 256, 0, stream>>>(vbar, attn);
  topattn<<<NBH, 256, 0, stream>>>(Qb, Kb, Vb, tidx, attn);
  gemm128<0><<<g, 256, 0, stream>>>(attn, wo, bo, out);
}

// Round 2
// 471.943 us; speedup vs baseline: 2.7177x; 2.7177x over previous
//
#include <hip/hip_runtime.h>
#include <hip/hip_bf16.h>
#include <math.h>

// B=8, S=2048, D=512, H=8, Dh=64, u = 5*ceil(ln(2048)) = 40
#define NB 8
#define NS 2048
#define ND 512
#define NH 8
#define DHD 64
#define NU 40
#define NBH 64
#define NM 16384  // NB*NS

typedef __attribute__((ext_vector_type(8))) short short8;
typedef __attribute__((ext_vector_type(4))) short short4v;
typedef __attribute__((ext_vector_type(4))) float f32x4;

__device__ __forceinline__ short f2bf(float f) {
  __hip_bfloat16 h = __float2bfloat16(f);
  return *reinterpret_cast<short*>(&h);
}
__device__ __forceinline__ float bf2f(short s) {
  __hip_bfloat16 h;
  *reinterpret_cast<short*>(&h) = s;
  return __bfloat162float(h);
}

// ---------------------------------------------------------------------------
// x [16384][512] f32 -> Xs [16384][1024] bf16 ([hi(512) | lo(512)])
// ---------------------------------------------------------------------------
__global__ void splitx(const float* __restrict__ x, short* __restrict__ Xs) {
  int i = blockIdx.x * 256 + threadIdx.x;  // chunk of 4 floats; 2097152 total
  const float4 v = *(const float4*)(x + (size_t)i * 4);
  int row = i >> 7;
  int col = (i & 127) << 2;
  float vv[4] = {v.x, v.y, v.z, v.w};
  short4v hi, lo;
#pragma unroll
  for (int j = 0; j < 4; ++j) {
    short h = f2bf(vv[j]);
    hi[j] = h;
    lo[j] = f2bf(vv[j] - bf2f(h));
  }
  *(short4v*)(Xs + (size_t)row * 1024 + col) = hi;
  *(short4v*)(Xs + (size_t)row * 1024 + 512 + col) = lo;
}

// ---------------------------------------------------------------------------
// W [512][512] f32 -> Wts[w] [512][1024] bf16 transposed ([n][hi(512)|lo(512)])
// ---------------------------------------------------------------------------
__global__ void wsplit(const float* __restrict__ w0, const float* __restrict__ w1,
                       const float* __restrict__ w2, const float* __restrict__ w3,
                       short* __restrict__ Wts) {
  const float* W = blockIdx.y == 0 ? w0 : blockIdx.y == 1 ? w1 : blockIdx.y == 2 ? w2 : w3;
  short* dst = Wts + (size_t)blockIdx.y * 512 * 1024;
  __shared__ float tile[32][33];
  int bx = blockIdx.x & 15, by = blockIdx.x >> 4;
  int k0 = bx * 32, n0 = by * 32;
  int r = threadIdx.x >> 3, cg = (threadIdx.x & 7) * 4;
  const float4 v = *(const float4*)(W + (size_t)(k0 + r) * 512 + n0 + cg);
  tile[r][cg] = v.x; tile[r][cg + 1] = v.y; tile[r][cg + 2] = v.z; tile[r][cg + 3] = v.w;
  __syncthreads();
#pragma unroll
  for (int j = 0; j < 4; ++j) {
    int kk = cg + j;
    float f = tile[kk][r];
    short h = f2bf(f);
    dst[(size_t)(n0 + r) * 1024 + k0 + kk] = h;
    dst[(size_t)(n0 + r) * 1024 + 512 + k0 + kk] = f2bf(f - bf2f(h));
  }
}

// ---------------------------------------------------------------------------
// Split-bf16 MFMA GEMM: C[16384][512] = X(hi+lo) @ W(hi+lo) + bias
// 3 terms: hi*hi + hi*lo + lo*hi. BM=BN=128, BK=32, 4 waves (2x2 of 64x64).
// MODE 1: QKV fused (grid.y 0..11), writes head-split hi/lo arrays [bh][s][128]
// MODE 0: output GEMM, writes fp32 row-major.
// ---------------------------------------------------------------------------
template <int MODE>
__global__ __launch_bounds__(256) void gemm_mfma(
    const short* __restrict__ A, const short* __restrict__ Wts,
    const float* __restrict__ b0, const float* __restrict__ b1, const float* __restrict__ b2,
    short* __restrict__ Qs, short* __restrict__ Ks, short* __restrict__ Vs,
    float* __restrict__ Cout) {
  __shared__ short As[128][64];  // row = [hi(32)|lo(32)], 16B chunks XOR-swizzled by (r&7)
  __shared__ short Bs[128][64];
  const int tid = threadIdx.x;
  const int m0 = blockIdx.x * 128;
  const int bn = blockIdx.y;
  const int wsel = MODE == 0 ? 3 : (bn >> 2);
  const int n0 = (MODE == 0 ? bn : (bn & 3)) * 128;
  const short* Wb = Wts + (size_t)wsel * 512 * 1024;
  const float* bias = MODE == 0 ? b0 : (wsel == 0 ? b0 : wsel == 1 ? b1 : b2);

  const int w = tid >> 6, l = tid & 63;
  const int wm = (w >> 1) * 64, wn = (w & 1) * 64;
  const int fr = l & 15, fk = l >> 4;

  f32x4 acc[4][4];
  const f32x4 zz = {0.f, 0.f, 0.f, 0.f};
#pragma unroll
  for (int i = 0; i < 4; ++i)
#pragma unroll
    for (int j = 0; j < 4; ++j) acc[i][j] = zz;

  for (int kt = 0; kt < 512; kt += 32) {
#pragma unroll
    for (int p = 0; p < 4; ++p) {
      int idx = tid + (p << 8);
      int r = idx >> 3, ch = idx & 7;
      int sc = (ch < 4) ? (kt + ch * 8) : (512 + kt + (ch - 4) * 8);
      *(short8*)&As[r][(ch ^ (r & 7)) << 3] = *(const short8*)(A + (size_t)(m0 + r) * 1024 + sc);
      *(short8*)&Bs[r][(ch ^ (r & 7)) << 3] = *(const short8*)(Wb + (size_t)(n0 + r) * 1024 + sc);
    }
    __syncthreads();
    short8 ah[4], al[4], bh[4], bl[4];
#pragma unroll
    for (int mf = 0; mf < 4; ++mf) {
      int r = wm + mf * 16 + fr;
      ah[mf] = *(const short8*)&As[r][(fk ^ (r & 7)) << 3];
      al[mf] = *(const short8*)&As[r][((4 + fk) ^ (r & 7)) << 3];
    }
#pragma unroll
    for (int nf = 0; nf < 4; ++nf) {
      int r = wn + nf * 16 + fr;
      bh[nf] = *(const short8*)&Bs[r][(fk ^ (r & 7)) << 3];
      bl[nf] = *(const short8*)&Bs[r][((4 + fk) ^ (r & 7)) << 3];
    }
#pragma unroll
    for (int mf = 0; mf < 4; ++mf)
#pragma unroll
      for (int nf = 0; nf < 4; ++nf) {
        acc[mf][nf] = __builtin_amdgcn_mfma_f32_16x16x32_bf16(ah[mf], bh[nf], acc[mf][nf], 0, 0, 0);
        acc[mf][nf] = __builtin_amdgcn_mfma_f32_16x16x32_bf16(ah[mf], bl[nf], acc[mf][nf], 0, 0, 0);
        acc[mf][nf] = __builtin_amdgcn_mfma_f32_16x16x32_bf16(al[mf], bh[nf], acc[mf][nf], 0, 0, 0);
      }
    __syncthreads();
  }
#pragma unroll
  for (int mf = 0; mf < 4; ++mf)
#pragma unroll
    for (int nf = 0; nf < 4; ++nf) {
      int cfull = n0 + wn + nf * 16 + fr;
      float bv_ = bias[cfull];
#pragma unroll
      for (int j = 0; j < 4; ++j) {
        int m = m0 + wm + mf * 16 + fk * 4 + j;
        float v = acc[mf][nf][j] + bv_;
        if (MODE == 0) {
          Cout[(size_t)m * 512 + cfull] = v;
        } else {
          int b = m >> 11, s = m & 2047, h = cfull >> 6, dh = cfull & 63;
          short* dst = (wsel == 0 ? Qs : wsel == 1 ? Ks : Vs) +
                       ((size_t)((b << 3) + h) * 2048 + s) * 128;
          short hi2 = f2bf(v);
          dst[dh] = hi2;
          dst[64 + dh] = f2bf(v - bf2f(hi2));
        }
      }
    }
}

// ---------------------------------------------------------------------------
// Column means of K and V (from hi+lo): kbar f32, vbar split bf16
// ---------------------------------------------------------------------------
__global__ __launch_bounds__(256) void colmeans(const short* __restrict__ Ks,
                                                const short* __restrict__ Vs,
                                                float* __restrict__ kbar,
                                                short* __restrict__ vbar_s) {
  const int bh = blockIdx.x;
  const int dd = threadIdx.x & 63, c = threadIdx.x >> 6;
  const short* Kb = Ks + (size_t)bh * 2048 * 128;
  const short* Vb = Vs + (size_t)bh * 2048 * 128;
  float sk = 0.f, sv = 0.f;
  for (int s = c * 512; s < (c + 1) * 512; ++s) {
    sk += bf2f(Kb[(size_t)s * 128 + dd]) + bf2f(Kb[(size_t)s * 128 + 64 + dd]);
    sv += bf2f(Vb[(size_t)s * 128 + dd]) + bf2f(Vb[(size_t)s * 128 + 64 + dd]);
  }
  __shared__ float rk[4][64], rv[4][64];
  rk[c][dd] = sk; rv[c][dd] = sv;
  __syncthreads();
  if (c == 0) {
    kbar[bh * 64 + dd] = (rk[0][dd] + rk[1][dd] + rk[2][dd] + rk[3][dd]) * (1.f / 2048.f);
    float vm = (rv[0][dd] + rv[1][dd] + rv[2][dd] + rv[3][dd]) * (1.f / 2048.f);
    short h = f2bf(vm);
    vbar_s[bh * 128 + dd] = h;
    vbar_s[bh * 128 + 64 + dd] = f2bf(vm - bf2f(h));
  }
}

// ---------------------------------------------------------------------------
// QK^T row-max via split-bf16 MFMA + fused M = (max - q.kbar)/8.
// Block: 64 q-rows x all 2048 keys; 4 waves each own 32 keys per 128-key tile.
// ---------------------------------------------------------------------------
__global__ __launch_bounds__(256) void qkmax(const short* __restrict__ Qs,
                                             const short* __restrict__ Ks,
                                             const float* __restrict__ kbar,
                                             float* __restrict__ Mval) {
  __shared__ short Qt[64][128];   // 256B rows, 16 chunks XOR (r&15)
  __shared__ short Kt[128][128];
  __shared__ float red[4][64];
  const int tid = threadIdx.x;
  const int bh = blockIdx.y, q0 = blockIdx.x * 64;
  const short* Qb = Qs + ((size_t)bh * 2048 + q0) * 128;
  const short* Kb = Ks + (size_t)bh * 2048 * 128;

#pragma unroll
  for (int p = 0; p < 4; ++p) {
    int idx = tid + (p << 8);
    int r = idx >> 4, ch = idx & 15;
    *(short8*)&Qt[r][(ch ^ (r & 15)) << 3] = *(const short8*)(Qb + (size_t)r * 128 + ch * 8);
  }
  __syncthreads();

  const int w = tid >> 6, l = tid & 63;
  const int fr = l & 15, fk = l >> 4;

  short8 qf[4][2][2];  // [mf][hi/lo][k0]
#pragma unroll
  for (int mf = 0; mf < 4; ++mf) {
    int r = mf * 16 + fr;
#pragma unroll
    for (int h = 0; h < 2; ++h)
#pragma unroll
      for (int k0 = 0; k0 < 2; ++k0) {
        int ch = h * 8 + k0 * 4 + fk;
        qf[mf][h][k0] = *(const short8*)&Qt[r][(ch ^ (r & 15)) << 3];
      }
  }

  f32x4 rmax[4];
  const f32x4 neg = {-1e30f, -1e30f, -1e30f, -1e30f};
#pragma unroll
  for (int mf = 0; mf < 4; ++mf) rmax[mf] = neg;
  const f32x4 zz = {0.f, 0.f, 0.f, 0.f};

  for (int t = 0; t < 16; ++t) {
    __syncthreads();
#pragma unroll
    for (int p = 0; p < 8; ++p) {
      int idx = tid + (p << 8);
      int r = idx >> 4, ch = idx & 15;
      *(short8*)&Kt[r][(ch ^ (r & 15)) << 3] =
          *(const short8*)(Kb + (size_t)(t * 128 + r) * 128 + ch * 8);
    }
    __syncthreads();

    short8 kf[2][2][2];
#pragma unroll
    for (int nf = 0; nf < 2; ++nf) {
      int r = w * 32 + nf * 16 + fr;
#pragma unroll
      for (int h = 0; h < 2; ++h)
#pragma unroll
        for (int k0 = 0; k0 < 2; ++k0) {
          int ch = h * 8 + k0 * 4 + fk;
          kf[nf][h][k0] = *(const short8*)&Kt[r][(ch ^ (r & 15)) << 3];
        }
    }
#pragma unroll
    for (int mf = 0; mf < 4; ++mf) {
      f32x4 a0 = zz, a1 = zz;
#pragma unroll
      for (int k0 = 0; k0 < 2; ++k0) {
        a0 = __builtin_amdgcn_mfma_f32_16x16x32_bf16(qf[mf][0][k0], kf[0][0][k0], a0, 0, 0, 0);
        a0 = __builtin_amdgcn_mfma_f32_16x16x32_bf16(qf[mf][0][k0], kf[0][1][k0], a0, 0, 0, 0);
        a0 = __builtin_amdgcn_mfma_f32_16x16x32_bf16(qf[mf][1][k0], kf[0][0][k0], a0, 0, 0, 0);
        a1 = __builtin_amdgcn_mfma_f32_16x16x32_bf16(qf[mf][0][k0], kf[1][0][k0], a1, 0, 0, 0);
        a1 = __builtin_amdgcn_mfma_f32_16x16x32_bf16(qf[mf][0][k0], kf[1][1][k0], a1, 0, 0, 0);
        a1 = __builtin_amdgcn_mfma_f32_16x16x32_bf16(qf[mf][1][k0], kf[1][0][k0], a1, 0, 0, 0);
      }
#pragma unroll
      for (int j = 0; j < 4; ++j)
        rmax[mf][j] = fmaxf(rmax[mf][j], fmaxf(a0[j], a1[j]));
    }
  }

#pragma unroll
  for (int mf = 0; mf < 4; ++mf)
#pragma unroll
    for (int j = 0; j < 4; ++j) {
      float r = rmax[mf][j];
      r = fmaxf(r, __shfl_xor(r, 1, 64));
      r = fmaxf(r, __shfl_xor(r, 2, 64));
      r = fmaxf(r, __shfl_xor(r, 4, 64));
      r = fmaxf(r, __shfl_xor(r, 8, 64));
      if (fr == 0) red[w][mf * 16 + fk * 4 + j] = r;
    }
  __syncthreads();
  if (tid < 64) {
    float mx = fmaxf(fmaxf(red[0][tid], red[1][tid]), fmaxf(red[2][tid], red[3][tid]));
    const float* kb = kbar + bh * 64;
    float dot = 0.f;
    int r = tid;
    for (int c = 0; c < 64; ++c) {
      int cc = (((c >> 3) ^ (r & 15)) << 3) | (c & 7);
      int cc2 = ((((c + 64) >> 3) ^ (r & 15)) << 3) | (c & 7);
      dot += (bf2f(Qt[r][cc]) + bf2f(Qt[r][cc2])) * kb[c];
    }
    Mval[(size_t)bh * 2048 + q0 + tid] = (mx - dot) * 0.125f;
  }
}

// ---------------------------------------------------------------------------
// top-40 per (bh) by M, ties -> lower index
// ---------------------------------------------------------------------------
__global__ __launch_bounds__(256) void topk40(const float* __restrict__ Mval,
                                              int* __restrict__ tidx) {
  const int bh = blockIdx.x;
  __shared__ float v[2048];
  __shared__ float wv_[4];
  __shared__ int wi_[4];
  const int tid = threadIdx.x;
  for (int i = tid; i < 2048; i += 256) v[i] = Mval[(size_t)bh * 2048 + i];
  __syncthreads();
  for (int it = 0; it < NU; ++it) {
    float best = -INFINITY;
    int bi = 1 << 30;
    for (int i = tid; i < 2048; i += 256) {
      float x = v[i];
      if (x > best || (x == best && i < bi)) { best = x; bi = i; }
    }
    for (int off = 1; off < 64; off <<= 1) {
      float ov = __shfl_xor(best, off, 64);
      int oi = __shfl_xor(bi, off, 64);
      if (ov > best || (ov == best && oi < bi)) { best = ov; bi = oi; }
    }
    if ((tid & 63) == 0) { wv_[tid >> 6] = best; wi_[tid >> 6] = bi; }
    __syncthreads();
    if (tid == 0) {
      float bb = wv_[0]; int bbi = wi_[0];
      for (int ww = 1; ww < 4; ++ww)
        if (wv_[ww] > bb || (wv_[ww] == bb && wi_[ww] < bbi)) { bb = wv_[ww]; bbi = wi_[ww]; }
      tidx[bh * NU + it] = bbi;
      v[bbi] = -INFINITY;
    }
    __syncthreads();
  }
}

// ---------------------------------------------------------------------------
// attn_s[row][hi|lo 1024] = vbar split, all rows
// ---------------------------------------------------------------------------
__global__ void fillmean(const short* __restrict__ vbar_s, short* __restrict__ attn_s) {
  size_t i = (size_t)blockIdx.x * 256 + threadIdx.x;  // 16384*128 chunks
  int row = (int)(i >> 7);
  int cc = (int)(i & 127);
  int part = cc >> 6;
  int c9 = (cc & 63) << 3;
  int h = c9 >> 6, dd = c9 & 63;
  int b = row >> 11;
  *(short8*)(attn_s + i * 8) =
      *(const short8*)(vbar_s + (size_t)((b << 3) + h) * 128 + part * 64 + dd);
}

// ---------------------------------------------------------------------------
// Dense attention for 40 selected queries, key-split over 4 chunks (partials)
// ---------------------------------------------------------------------------
__global__ __launch_bounds__(256) void topattn1(const short* __restrict__ Qs,
                                                const short* __restrict__ Ks,
                                                const short* __restrict__ Vs,
                                                const int* __restrict__ topidx,
                                                float* __restrict__ pacc,
                                                float* __restrict__ pm,
                                                float* __restrict__ pl) {
  __shared__ float qs[40][68];
  __shared__ float Kst[64][132];
  __shared__ float Vsh[128][68];
  __shared__ float st[40][132];
  __shared__ float m_s[40], l_s[40], r_s[40];
  __shared__ int tix[40];
  const int tid = threadIdx.x;
  const int bh = blockIdx.x, kc = blockIdx.y;
  const short* Kb = Ks + (size_t)bh * 2048 * 128;
  const short* Vb = Vs + (size_t)bh * 2048 * 128;

  if (tid < 40) {
    tix[tid] = topidx[bh * NU + tid];
    m_s[tid] = -INFINITY;
    l_s[tid] = 0.f;
  }
  __syncthreads();
  for (int i = tid; i < 40 * 64; i += 256) {
    int q = i >> 6, dd2 = i & 63;
    const short* qp = Qs + ((size_t)bh * 2048 + tix[q]) * 128;
    qs[q][dd2] = bf2f(qp[dd2]) + bf2f(qp[64 + dd2]);
  }
  const int tx = tid & 31, ty = tid >> 5;
  const int d = tid & 63, qb = tid >> 6;
  float acc[10];
#pragma unroll
  for (int j = 0; j < 10; ++j) acc[j] = 0.f;
  __syncthreads();

  for (int t = 0; t < 4; ++t) {
    int krow0 = kc * 512 + t * 128;
#pragma unroll
    for (int p = 0; p < 4; ++p) {
      int idx = tid + (p << 8);
      int r = idx >> 3, cg = (idx & 7) << 3;
      const short8 kh = *(const short8*)(Kb + (size_t)(krow0 + r) * 128 + cg);
      const short8 kl = *(const short8*)(Kb + (size_t)(krow0 + r) * 128 + 64 + cg);
      const short8 vh = *(const short8*)(Vb + (size_t)(krow0 + r) * 128 + cg);
      const short8 vl = *(const short8*)(Vb + (size_t)(krow0 + r) * 128 + 64 + cg);
#pragma unroll
      for (int j = 0; j < 8; ++j) {
        Kst[cg + j][r] = bf2f(kh[j]) + bf2f(kl[j]);
        Vsh[r][cg + j] = bf2f(vh[j]) + bf2f(vl[j]);
      }
    }
    __syncthreads();

    {
      float c5[5][4];
#pragma unroll
      for (int i = 0; i < 5; ++i)
#pragma unroll
        for (int j = 0; j < 4; ++j) c5[i][j] = 0.f;
      for (int dd = 0; dd < 64; ++dd) {
        const float4 b4 = *(const float4*)&Kst[dd][tx << 2];
#pragma unroll
        for (int i = 0; i < 5; ++i) {
          float a = qs[ty * 5 + i][dd];
          c5[i][0] = fmaf(a, b4.x, c5[i][0]);
          c5[i][1] = fmaf(a, b4.y, c5[i][1]);
          c5[i][2] = fmaf(a, b4.z, c5[i][2]);
          c5[i][3] = fmaf(a, b4.w, c5[i][3]);
        }
      }
#pragma unroll
      for (int i = 0; i < 5; ++i) {
        float4 o;
        o.x = c5[i][0] * 0.125f; o.y = c5[i][1] * 0.125f;
        o.z = c5[i][2] * 0.125f; o.w = c5[i][3] * 0.125f;
        *(float4*)&st[ty * 5 + i][tx << 2] = o;
      }
    }
    __syncthreads();

    if (tid < 40) {
      float mold = m_s[tid];
      float tm = st[tid][0];
      for (int kk = 1; kk < 128; ++kk) tm = fmaxf(tm, st[tid][kk]);
      float mnew = fmaxf(mold, tm);
      float r = __expf(mold - mnew);
      float sum = 0.f;
      for (int kk = 0; kk < 128; ++kk) {
        float ww = __expf(st[tid][kk] - mnew);
        st[tid][kk] = ww;
        sum += ww;
      }
      l_s[tid] = l_s[tid] * r + sum;
      m_s[tid] = mnew;
      r_s[tid] = r;
    }
    __syncthreads();

#pragma unroll
    for (int j = 0; j < 10; ++j) {
      int q = qb + (j << 2);
      float a = 0.f;
#pragma unroll
      for (int kk = 0; kk < 128; kk += 4) {
        float4 ww = *(const float4*)&st[q][kk];
        a = fmaf(ww.x, Vsh[kk + 0][d], a);
        a = fmaf(ww.y, Vsh[kk + 1][d], a);
        a = fmaf(ww.z, Vsh[kk + 2][d], a);
        a = fmaf(ww.w, Vsh[kk + 3][d], a);
      }
      acc[j] = acc[j] * r_s[q] + a;
    }
    __syncthreads();
  }

  int pcb = bh * 4 + kc;
#pragma unroll
  for (int j = 0; j < 10; ++j) {
    int q = qb + (j << 2);
    pacc[((size_t)pcb * NU + q) * 64 + d] = acc[j];
  }
  if (tid < 40) {
    pm[pcb * NU + tid] = m_s[tid];
    pl[pcb * NU + tid] = l_s[tid];
  }
}

// ---------------------------------------------------------------------------
// Combine 4 key-chunk partials; write split bf16 rows into attn_s
// ---------------------------------------------------------------------------
__global__ __launch_bounds__(256) void topcombine(const float* __restrict__ pacc,
                                                  const float* __restrict__ pm,
                                                  const float* __restrict__ pl,
                                                  const int* __restrict__ topidx,
                                                  short* __restrict__ attn_s) {
  const int bh = blockIdx.x;
  const int d = threadIdx.x & 63, qb = threadIdx.x >> 6;
  const int b = bh >> 3, hh = bh & 7;
#pragma unroll
  for (int j = 0; j < 10; ++j) {
    int q = qb + (j << 2);
    float m0 = pm[(bh * 4 + 0) * NU + q], m1 = pm[(bh * 4 + 1) * NU + q];
    float m2 = pm[(bh * 4 + 2) * NU + q], m3 = pm[(bh * 4 + 3) * NU + q];
    float mx = fmaxf(fmaxf(m0, m1), fmaxf(m2, m3));
    float e0 = __expf(m0 - mx), e1 = __expf(m1 - mx);
    float e2 = __expf(m2 - mx), e3 = __expf(m3 - mx);
    float L = pl[(bh * 4 + 0) * NU + q] * e0 + pl[(bh * 4 + 1) * NU + q] * e1 +
              pl[(bh * 4 + 2) * NU + q] * e2 + pl[(bh * 4 + 3) * NU + q] * e3;
    float o = (pacc[((size_t)(bh * 4 + 0) * NU + q) * 64 + d] * e0 +
               pacc[((size_t)(bh * 4 + 1) * NU + q) * 64 + d] * e1 +
               pacc[((size_t)(bh * 4 + 2) * NU + q) * 64 + d] * e2 +
               pacc[((size_t)(bh * 4 + 3) * NU + q) * 64 + d] * e3) / L;
    int row = b * 2048 + topidx[bh * NU + q];
    short hi = f2bf(o);
    attn_s[(size_t)row * 1024 + hh * 64 + d] = hi;
    attn_s[(size_t)row * 1024 + 512 + hh * 64 + d] = f2bf(o - bf2f(hi));
  }
}

// ---------------------------------------------------------------------------
extern "C" void kernel_launch(void* const* d_in, const int* in_sizes, int n_in,
                              void* d_out, int out_size, void* d_ws, size_t ws_size,
                              hipStream_t stream) {
  (void)in_sizes; (void)n_in; (void)out_size; (void)ws_size;
  const float* x  = (const float*)d_in[0];
  const float* wq = (const float*)d_in[1];
  const float* bq = (const float*)d_in[2];
  const float* wk = (const float*)d_in[3];
  const float* bk = (const float*)d_in[4];
  const float* wv = (const float*)d_in[5];
  const float* bv = (const float*)d_in[6];
  const float* wo = (const float*)d_in[7];
  const float* bo = (const float*)d_in[8];
  float* out = (float*)d_out;

  short* Xs = (short*)d_ws;                                  // 16384*1024
  short* attn_s = Xs;                                        // alias (disjoint lifetime)
  short* Wts = Xs + (size_t)16384 * 1024;                    // 4*512*1024
  short* Qsb = Wts + (size_t)4 * 512 * 1024;                 // 64*2048*128
  short* Ksb = Qsb + (size_t)NBH * NS * 128;
  short* Vsb = Ksb + (size_t)NBH * NS * 128;
  float* Mval = (float*)(Vsb + (size_t)NBH * NS * 128);      // 131072
  float* kbar = Mval + (size_t)NBH * NS;                     // 4096
  short* vbar_s = (short*)(kbar + NBH * 64);                 // 8192 shorts
  int* tidx = (int*)(vbar_s + NBH * 128);                    // 2560
  float* pacc = (float*)(tidx + NBH * NU);                   // 64*4*40*64
  float* pm = pacc + (size_t)NBH * 4 * NU * 64;
  float* pl = pm + NBH * 4 * NU;

  splitx<<<8192, 256, 0, stream>>>(x, Xs);
  wsplit<<<dim3(256, 4), 256, 0, stream>>>(wq, wk, wv, wo, Wts);
  gemm_mfma<1><<<dim3(128, 12), 256, 0, stream>>>(Xs, Wts, bq, bk, bv, Qsb, Ksb, Vsb, nullptr);
  colmeans<<<NBH, 256, 0, stream>>>(Ksb, Vsb, kbar, vbar_s);
  qkmax<<<dim3(32, NBH), 256, 0, stream>>>(Qsb, Ksb, kbar, Mval);
  topk40<<<NBH, 256, 0, stream>>>(Mval, tidx);
  fillmean<<<8192, 256, 0, stream>>>(vbar_s, attn_s);
  topattn1<<<dim3(NBH, 4), 256, 0, stream>>>(Qsb, Ksb, Vsb, tidx, pacc, pm, pl);
  topcombine<<<NBH, 256, 0, stream>>>(pacc, pm, pl, tidx, attn_s);
  gemm_mfma<0><<<dim3(128, 4), 256, 0, stream>>>(attn_s, Wts, bo, nullptr, nullptr,
                                                 nullptr, nullptr, nullptr, out);
}

// Round 3
// 438.143 us; speedup vs baseline: 2.9274x; 1.0771x over previous
//
#include <hip/hip_runtime.h>
#include <hip/hip_bf16.h>
#include <math.h>

// B=8, S=2048, D=512, H=8, Dh=64, u = 5*ceil(ln(2048)) = 40
#define NB 8
#define NS 2048
#define ND 512
#define NH 8
#define DHD 64
#define NU 40
#define NBH 64
#define NM 16384  // NB*NS

typedef __attribute__((ext_vector_type(8))) short short8;
typedef __attribute__((ext_vector_type(4))) short short4v;
typedef __attribute__((ext_vector_type(4))) float f32x4;

__device__ __forceinline__ short f2bf(float f) {
  __hip_bfloat16 h = __float2bfloat16(f);
  return *reinterpret_cast<short*>(&h);
}
__device__ __forceinline__ float bf2f(short s) {
  __hip_bfloat16 h;
  *reinterpret_cast<short*>(&h) = s;
  return __bfloat162float(h);
}

// async global->LDS, 16B per lane; LDS dest = wave-uniform base + lane*16
__device__ __forceinline__ void gload_lds16(const short* g, short* l) {
  __builtin_amdgcn_global_load_lds(
      (const __attribute__((address_space(1))) unsigned int*)g,
      (__attribute__((address_space(3))) unsigned int*)l, 16, 0, 0);
}

// ---------------------------------------------------------------------------
// x [16384][512] f32 -> Xs [16384][1024] bf16 ([hi(512) | lo(512)])
// ---------------------------------------------------------------------------
__global__ void splitx(const float* __restrict__ x, short* __restrict__ Xs) {
  int i = blockIdx.x * 256 + threadIdx.x;  // chunk of 4 floats; 2097152 total
  const float4 v = *(const float4*)(x + (size_t)i * 4);
  int row = i >> 7;
  int col = (i & 127) << 2;
  float vv[4] = {v.x, v.y, v.z, v.w};
  short4v hi, lo;
#pragma unroll
  for (int j = 0; j < 4; ++j) {
    short h = f2bf(vv[j]);
    hi[j] = h;
    lo[j] = f2bf(vv[j] - bf2f(h));
  }
  *(short4v*)(Xs + (size_t)row * 1024 + col) = hi;
  *(short4v*)(Xs + (size_t)row * 1024 + 512 + col) = lo;
}

// ---------------------------------------------------------------------------
// W [512][512] f32 -> Wts[w] [512][1024] bf16 transposed ([n][hi(512)|lo(512)])
// w = 0,1,2 -> wq,wk,wv   (wo stays f32)
// ---------------------------------------------------------------------------
__global__ void wsplit(const float* __restrict__ w0, const float* __restrict__ w1,
                       const float* __restrict__ w2, short* __restrict__ Wts) {
  const float* W = blockIdx.y == 0 ? w0 : blockIdx.y == 1 ? w1 : w2;
  short* dst = Wts + (size_t)blockIdx.y * 512 * 1024;
  __shared__ float tile[32][33];
  int bx = blockIdx.x & 15, by = blockIdx.x >> 4;
  int k0 = bx * 32, n0 = by * 32;
  int r = threadIdx.x >> 3, cg = (threadIdx.x & 7) * 4;
  const float4 v = *(const float4*)(W + (size_t)(k0 + r) * 512 + n0 + cg);
  tile[r][cg] = v.x; tile[r][cg + 1] = v.y; tile[r][cg + 2] = v.z; tile[r][cg + 3] = v.w;
  __syncthreads();
#pragma unroll
  for (int j = 0; j < 4; ++j) {
    int kk = cg + j;
    float f = tile[kk][r];
    short h = f2bf(f);
    dst[(size_t)(n0 + r) * 1024 + k0 + kk] = h;
    dst[(size_t)(n0 + r) * 1024 + 512 + k0 + kk] = f2bf(f - bf2f(h));
  }
}

// ---------------------------------------------------------------------------
// Split-bf16 MFMA GEMM (QKV fused): C = X(hi+lo) @ W(hi+lo) + bias
// BM=BN=128, BK=32(real), 4 waves (2x2 of 64x64). Dbuf LDS via global_load_lds.
// Swapped-operand MFMA: D row = feature(n), col = x-row(m) -> packed 8B stores.
// Grid: 1536 blocks 1D, XCD-swizzled (192 per XCD, m-major within XCD).
// ---------------------------------------------------------------------------
__global__ __launch_bounds__(256, 2) void qkvgemm(
    const short* __restrict__ A, const short* __restrict__ Wts,
    const float* __restrict__ bq, const float* __restrict__ bk,
    const float* __restrict__ bv, short* __restrict__ Qs,
    short* __restrict__ Ks, short* __restrict__ Vs) {
  __shared__ short As[2][128][64];
  __shared__ short Bs[2][128][64];
  const int bid = blockIdx.x;
  const int wgid = (bid & 7) * 192 + (bid >> 3);  // 1536 = 8*192 exact
  const int mb = wgid / 12, y = wgid % 12;
  const int m0 = mb * 128;
  const int wsel = y >> 2;
  const int n0 = (y & 3) * 128;
  const short* Wb = Wts + (size_t)wsel * 512 * 1024;
  const float* bias = wsel == 0 ? bq : wsel == 1 ? bk : bv;
  short* dstbase = wsel == 0 ? Qs : wsel == 1 ? Ks : Vs;

  const int tid = threadIdx.x;
  const int w = tid >> 6, lane = tid & 63;
  const int wm = (w >> 1) * 64, wn = (w & 1) * 64;
  const int fr = lane & 15, fk = lane >> 4;

  f32x4 acc[4][4];
  const f32x4 zz = {0.f, 0.f, 0.f, 0.f};
#pragma unroll
  for (int i = 0; i < 4; ++i)
#pragma unroll
    for (int j = 0; j < 4; ++j) acc[i][j] = zz;

  // stage one 128x32(real-k) hi+lo tile pair into buf
  auto stage = [&](int buf, int kt) {
#pragma unroll
    for (int p = 0; p < 4; ++p) {
      int idx = (p * 4 + w) * 64 + lane;   // 0..1023
      int r = idx >> 3, c = idx & 7;
      int cs = c ^ (r & 7);                // inverse-swizzled source chunk
      int sc = (cs < 4) ? (kt + cs * 8) : (512 + kt + (cs - 4) * 8);
      short* lA = &As[buf][0][0] + (p * 4 + w) * 512;
      short* lB = &Bs[buf][0][0] + (p * 4 + w) * 512;
      gload_lds16(A + (size_t)(m0 + r) * 1024 + sc, lA);
      gload_lds16(Wb + (size_t)(n0 + r) * 1024 + sc, lB);
    }
  };

  stage(0, 0);
  __syncthreads();
  for (int kt = 0; kt < 512; kt += 32) {
    int cur = (kt >> 5) & 1;
    if (kt + 32 < 512) stage(cur ^ 1, kt + 32);
    short8 ah[4], al[4], bh[4], bl[4];
#pragma unroll
    for (int mf = 0; mf < 4; ++mf) {
      int r = wm + mf * 16 + fr;
      ah[mf] = *(const short8*)&As[cur][r][(fk ^ (r & 7)) << 3];
      al[mf] = *(const short8*)&As[cur][r][((4 + fk) ^ (r & 7)) << 3];
    }
#pragma unroll
    for (int nf = 0; nf < 4; ++nf) {
      int r = wn + nf * 16 + fr;
      bh[nf] = *(const short8*)&Bs[cur][r][(fk ^ (r & 7)) << 3];
      bl[nf] = *(const short8*)&Bs[cur][r][((4 + fk) ^ (r & 7)) << 3];
    }
#pragma unroll
    for (int mf = 0; mf < 4; ++mf)
#pragma unroll
      for (int nf = 0; nf < 4; ++nf) {
        // swapped operands: D[n][m]; terms Whi*Xhi + Whi*Xlo + Wlo*Xhi
        acc[mf][nf] = __builtin_amdgcn_mfma_f32_16x16x32_bf16(bh[nf], ah[mf], acc[mf][nf], 0, 0, 0);
        acc[mf][nf] = __builtin_amdgcn_mfma_f32_16x16x32_bf16(bh[nf], al[mf], acc[mf][nf], 0, 0, 0);
        acc[mf][nf] = __builtin_amdgcn_mfma_f32_16x16x32_bf16(bl[nf], ah[mf], acc[mf][nf], 0, 0, 0);
      }
    __syncthreads();
  }

  // epilogue: lane holds (m = m0+wm+mf*16+fr) x (n = n0+wn+nf*16+fk*4+j, j=0..3)
#pragma unroll
  for (int mf = 0; mf < 4; ++mf) {
    int m = m0 + wm + mf * 16 + fr;
    int b = m >> 11, s = m & 2047;
#pragma unroll
    for (int nf = 0; nf < 4; ++nf) {
      int nb = n0 + wn + nf * 16 + fk * 4;
      float4 bi4 = *(const float4*)(bias + nb);
      int h = nb >> 6, dh = nb & 63;
      short* dst = dstbase + ((size_t)((b << 3) + h) * 2048 + s) * 128;
      short4v hi, lo;
      float bb[4] = {bi4.x, bi4.y, bi4.z, bi4.w};
#pragma unroll
      for (int j = 0; j < 4; ++j) {
        float v = acc[mf][nf][j] + bb[j];
        short hs = f2bf(v);
        hi[j] = hs;
        lo[j] = f2bf(v - bf2f(hs));
      }
      *(short4v*)(dst + dh) = hi;
      *(short4v*)(dst + 64 + dh) = lo;
    }
  }
}

// ---------------------------------------------------------------------------
// Column means of K and V (hi+lo): kbarf f32 [bh][64], vbarf f32 [bh][64]
// ---------------------------------------------------------------------------
__global__ __launch_bounds__(256) void colmeans(const short* __restrict__ K,
                                                const short* __restrict__ V,
                                                float* __restrict__ kbarf,
                                                float* __restrict__ vbarf) {
  const int bh = blockIdx.x;
  const int c = threadIdx.x & 15;   // 8-short column chunk
  const int g = threadIdx.x >> 4;   // row group
  const short* Kb = K + (size_t)bh * 2048 * 128;
  const short* Vb = V + (size_t)bh * 2048 * 128;
  float sk[8], sv[8];
#pragma unroll
  for (int e = 0; e < 8; ++e) { sk[e] = 0.f; sv[e] = 0.f; }
  for (int s = g * 128; s < g * 128 + 128; ++s) {
    short8 k8 = *(const short8*)(Kb + (size_t)s * 128 + c * 8);
    short8 v8 = *(const short8*)(Vb + (size_t)s * 128 + c * 8);
#pragma unroll
    for (int e = 0; e < 8; ++e) { sk[e] += bf2f(k8[e]); sv[e] += bf2f(v8[e]); }
  }
  __shared__ float rk[16][128], rv[16][128];
#pragma unroll
  for (int e = 0; e < 8; ++e) { rk[g][c * 8 + e] = sk[e]; rv[g][c * 8 + e] = sv[e]; }
  __syncthreads();
  if (threadIdx.x < 64) {
    int d = threadIdx.x;
    float a = 0.f, b2 = 0.f;
    for (int g2 = 0; g2 < 16; ++g2) {
      a += rk[g2][d] + rk[g2][64 + d];
      b2 += rv[g2][d] + rv[g2][64 + d];
    }
    kbarf[bh * 64 + d] = a * (1.f / 2048.f);
    vbarf[bh * 64 + d] = b2 * (1.f / 2048.f);
  }
}

// ---------------------------------------------------------------------------
// QK^T row-max via split-bf16 MFMA + fused M = (max - q.kbar)/8.
// 256 q-rows per block (wave owns 64), K dbuf-staged 128 keys/tile.
// Grid 512 1D, XCD-swizzled: 8 bh per XCD (K stays L2-resident).
// ---------------------------------------------------------------------------
__global__ __launch_bounds__(256, 2) void qkmax(const short* __restrict__ Qs,
                                                const short* __restrict__ Ks,
                                                const float* __restrict__ kbarf,
                                                float* __restrict__ Mval) {
  __shared__ short Kt[2][128][128];
  __shared__ float red[256];
  const int bid = blockIdx.x;
  const int wgid = (bid & 7) * 64 + (bid >> 3);  // 512 = 8*64 exact
  const int bh = wgid >> 3, q0 = (wgid & 7) * 256;
  const short* Qb = Qs + ((size_t)bh * 2048 + q0) * 128;
  const short* Kb = Ks + (size_t)bh * 2048 * 128;
  const int tid = threadIdx.x, w = tid >> 6, lane = tid & 63;
  const int fr = lane & 15, fk = lane >> 4;

  // Q fragments straight from global (L2-hot): wave w owns q rows w*64+mf*16+fr
  short8 qf[4][2][2];  // [mf][hi/lo][k0]
#pragma unroll
  for (int mf = 0; mf < 4; ++mf) {
    int row = w * 64 + mf * 16 + fr;
#pragma unroll
    for (int h = 0; h < 2; ++h)
#pragma unroll
      for (int k0 = 0; k0 < 2; ++k0) {
        int ch = h * 8 + k0 * 4 + fk;
        qf[mf][h][k0] = *(const short8*)(Qb + (size_t)row * 128 + ch * 8);
      }
  }

  f32x4 rmax[4];
  const f32x4 neg = {-1e30f, -1e30f, -1e30f, -1e30f};
#pragma unroll
  for (int mf = 0; mf < 4; ++mf) rmax[mf] = neg;
  const f32x4 zz = {0.f, 0.f, 0.f, 0.f};

  auto stageK = [&](int buf, int t) {
#pragma unroll
    for (int p = 0; p < 8; ++p) {
      int idx = (p * 4 + w) * 64 + lane;  // 0..2047
      int r = idx >> 4, c = idx & 15;
      int cs = c ^ (r & 15);
      short* lb = &Kt[buf][0][0] + (p * 4 + w) * 512;
      gload_lds16(Kb + (size_t)(t * 128 + r) * 128 + cs * 8, lb);
    }
  };

  stageK(0, 0);
  __syncthreads();
  for (int t = 0; t < 16; ++t) {
    int cur = t & 1;
    if (t < 15) stageK(cur ^ 1, t + 1);
#pragma unroll
    for (int nf = 0; nf < 8; ++nf) {
      int r = nf * 16 + fr;
      short8 kfh[2], kfl[2];
#pragma unroll
      for (int k0 = 0; k0 < 2; ++k0) {
        kfh[k0] = *(const short8*)&Kt[cur][r][((k0 * 4 + fk) ^ (r & 15)) << 3];
        kfl[k0] = *(const short8*)&Kt[cur][r][((8 + k0 * 4 + fk) ^ (r & 15)) << 3];
      }
#pragma unroll
      for (int mf = 0; mf < 4; ++mf) {
        f32x4 a = zz;
#pragma unroll
        for (int k0 = 0; k0 < 2; ++k0) {
          a = __builtin_amdgcn_mfma_f32_16x16x32_bf16(qf[mf][0][k0], kfh[k0], a, 0, 0, 0);
          a = __builtin_amdgcn_mfma_f32_16x16x32_bf16(qf[mf][0][k0], kfl[k0], a, 0, 0, 0);
          a = __builtin_amdgcn_mfma_f32_16x16x32_bf16(qf[mf][1][k0], kfh[k0], a, 0, 0, 0);
        }
#pragma unroll
        for (int j = 0; j < 4; ++j) rmax[mf][j] = fmaxf(rmax[mf][j], a[j]);
      }
    }
    __syncthreads();
  }

  // reduce over key lanes (col = lane&15), lane fr==0 holds q = w*64+mf*16+fk*4+j
#pragma unroll
  for (int mf = 0; mf < 4; ++mf)
#pragma unroll
    for (int j = 0; j < 4; ++j) {
      float r = rmax[mf][j];
      r = fmaxf(r, __shfl_xor(r, 1, 64));
      r = fmaxf(r, __shfl_xor(r, 2, 64));
      r = fmaxf(r, __shfl_xor(r, 4, 64));
      r = fmaxf(r, __shfl_xor(r, 8, 64));
      if (fr == 0) red[w * 64 + mf * 16 + fk * 4 + j] = r;
    }
  __syncthreads();

  // fused M = (max - q.kbar)/8, one thread per q-row
  {
    const short* qp = Qs + ((size_t)bh * 2048 + q0 + tid) * 128;
    const float* kb = kbarf + bh * 64;
    float dot = 0.f;
#pragma unroll
    for (int ch = 0; ch < 8; ++ch) {
      short8 hi = *(const short8*)(qp + ch * 8);
      short8 lo = *(const short8*)(qp + 64 + ch * 8);
#pragma unroll
      for (int e = 0; e < 8; ++e) dot += (bf2f(hi[e]) + bf2f(lo[e])) * kb[ch * 8 + e];
    }
    Mval[(size_t)bh * 2048 + q0 + tid] = (red[tid] - dot) * 0.125f;
  }
}

// ---------------------------------------------------------------------------
// top-40 per (bh) by M, ties -> lower index
// ---------------------------------------------------------------------------
__global__ __launch_bounds__(256) void topk40(const float* __restrict__ Mval,
                                              int* __restrict__ tidx) {
  const int bh = blockIdx.x;
  __shared__ float v[2048];
  __shared__ float wv_[4];
  __shared__ int wi_[4];
  const int tid = threadIdx.x;
  for (int i = tid; i < 2048; i += 256) v[i] = Mval[(size_t)bh * 2048 + i];
  __syncthreads();
  for (int it = 0; it < NU; ++it) {
    float best = -INFINITY;
    int bi = 1 << 30;
    for (int i = tid; i < 2048; i += 256) {
      float x = v[i];
      if (x > best || (x == best && i < bi)) { best = x; bi = i; }
    }
    for (int off = 1; off < 64; off <<= 1) {
      float ov = __shfl_xor(best, off, 64);
      int oi = __shfl_xor(bi, off, 64);
      if (ov > best || (ov == best && oi < bi)) { best = ov; bi = oi; }
    }
    if ((tid & 63) == 0) { wv_[tid >> 6] = best; wi_[tid >> 6] = bi; }
    __syncthreads();
    if (tid == 0) {
      float bb = wv_[0]; int bbi = wi_[0];
      for (int ww = 1; ww < 4; ++ww)
        if (wv_[ww] > bb || (wv_[ww] == bb && wi_[ww] < bbi)) { bb = wv_[ww]; bbi = wi_[ww]; }
      tidx[bh * NU + it] = bbi;
      v[bbi] = -INFINITY;
    }
    __syncthreads();
  }
}

// ---------------------------------------------------------------------------
// Dense attention for 40 selected queries, key-split over 4 chunks (partials)
// ---------------------------------------------------------------------------
__global__ __launch_bounds__(256) void topattn1(const short* __restrict__ Qs,
                                                const short* __restrict__ Ks,
                                                const short* __restrict__ Vs,
                                                const int* __restrict__ topidx,
                                                float* __restrict__ pacc,
                                                float* __restrict__ pm,
                                                float* __restrict__ pl) {
  __shared__ float qs[40][68];
  __shared__ float Kst[64][132];
  __shared__ float Vsh[128][68];
  __shared__ float st[40][132];
  __shared__ float m_s[40], l_s[40], r_s[40];
  __shared__ int tix[40];
  const int tid = threadIdx.x;
  const int bh = blockIdx.x, kc = blockIdx.y;
  const short* Kb = Ks + (size_t)bh * 2048 * 128;
  const short* Vb = Vs + (size_t)bh * 2048 * 128;

  if (tid < 40) {
    tix[tid] = topidx[bh * NU + tid];
    m_s[tid] = -INFINITY;
    l_s[tid] = 0.f;
  }
  __syncthreads();
  for (int i = tid; i < 40 * 64; i += 256) {
    int q = i >> 6, dd2 = i & 63;
    const short* qp = Qs + ((size_t)bh * 2048 + tix[q]) * 128;
    qs[q][dd2] = bf2f(qp[dd2]) + bf2f(qp[64 + dd2]);
  }
  const int tx = tid & 31, ty = tid >> 5;
  const int d = tid & 63, qb = tid >> 6;
  float acc[10];
#pragma unroll
  for (int j = 0; j < 10; ++j) acc[j] = 0.f;
  __syncthreads();

  for (int t = 0; t < 4; ++t) {
    int krow0 = kc * 512 + t * 128;
#pragma unroll
    for (int p = 0; p < 4; ++p) {
      int idx = tid + (p << 8);
      int r = idx >> 3, cg = (idx & 7) << 3;
      const short8 kh = *(const short8*)(Kb + (size_t)(krow0 + r) * 128 + cg);
      const short8 kl = *(const short8*)(Kb + (size_t)(krow0 + r) * 128 + 64 + cg);
      const short8 vh = *(const short8*)(Vb + (size_t)(krow0 + r) * 128 + cg);
      const short8 vl = *(const short8*)(Vb + (size_t)(krow0 + r) * 128 + 64 + cg);
#pragma unroll
      for (int j = 0; j < 8; ++j) {
        Kst[cg + j][r] = bf2f(kh[j]) + bf2f(kl[j]);
        Vsh[r][cg + j] = bf2f(vh[j]) + bf2f(vl[j]);
      }
    }
    __syncthreads();

    {
      float c5[5][4];
#pragma unroll
      for (int i = 0; i < 5; ++i)
#pragma unroll
        for (int j = 0; j < 4; ++j) c5[i][j] = 0.f;
      for (int dd = 0; dd < 64; ++dd) {
        const float4 b4 = *(const float4*)&Kst[dd][tx << 2];
#pragma unroll
        for (int i = 0; i < 5; ++i) {
          float a = qs[ty * 5 + i][dd];
          c5[i][0] = fmaf(a, b4.x, c5[i][0]);
          c5[i][1] = fmaf(a, b4.y, c5[i][1]);
          c5[i][2] = fmaf(a, b4.z, c5[i][2]);
          c5[i][3] = fmaf(a, b4.w, c5[i][3]);
        }
      }
#pragma unroll
      for (int i = 0; i < 5; ++i) {
        float4 o;
        o.x = c5[i][0] * 0.125f; o.y = c5[i][1] * 0.125f;
        o.z = c5[i][2] * 0.125f; o.w = c5[i][3] * 0.125f;
        *(float4*)&st[ty * 5 + i][tx << 2] = o;
      }
    }
    __syncthreads();

    if (tid < 40) {
      float mold = m_s[tid];
      float tm = st[tid][0];
      for (int kk = 1; kk < 128; ++kk) tm = fmaxf(tm, st[tid][kk]);
      float mnew = fmaxf(mold, tm);
      float r = __expf(mold - mnew);
      float sum = 0.f;
      for (int kk = 0; kk < 128; ++kk) {
        float ww = __expf(st[tid][kk] - mnew);
        st[tid][kk] = ww;
        sum += ww;
      }
      l_s[tid] = l_s[tid] * r + sum;
      m_s[tid] = mnew;
      r_s[tid] = r;
    }
    __syncthreads();

#pragma unroll
    for (int j = 0; j < 10; ++j) {
      int q = qb + (j << 2);
      float a = 0.f;
#pragma unroll
      for (int kk = 0; kk < 128; kk += 4) {
        float4 ww = *(const float4*)&st[q][kk];
        a = fmaf(ww.x, Vsh[kk + 0][d], a);
        a = fmaf(ww.y, Vsh[kk + 1][d], a);
        a = fmaf(ww.z, Vsh[kk + 2][d], a);
        a = fmaf(ww.w, Vsh[kk + 3][d], a);
      }
      acc[j] = acc[j] * r_s[q] + a;
    }
    __syncthreads();
  }

  int pcb = bh * 4 + kc;
#pragma unroll
  for (int j = 0; j < 10; ++j) {
    int q = qb + (j << 2);
    pacc[((size_t)pcb * NU + q) * 64 + d] = acc[j];
  }
  if (tid < 40) {
    pm[pcb * NU + tid] = m_s[tid];
    pl[pcb * NU + tid] = l_s[tid];
  }
}

// ---------------------------------------------------------------------------
// Combine 4 key-chunk partials -> tout[bh][40][64] f32
// ---------------------------------------------------------------------------
__global__ __launch_bounds__(256) void topcombine(const float* __restrict__ pacc,
                                                  const float* __restrict__ pm,
                                                  const float* __restrict__ pl,
                                                  float* __restrict__ tout) {
  const int bh = blockIdx.x;
  const int d = threadIdx.x & 63, qb = threadIdx.x >> 6;
#pragma unroll
  for (int j = 0; j < 10; ++j) {
    int q = qb + (j << 2);
    float m0 = pm[(bh * 4 + 0) * NU + q], m1 = pm[(bh * 4 + 1) * NU + q];
    float m2 = pm[(bh * 4 + 2) * NU + q], m3 = pm[(bh * 4 + 3) * NU + q];
    float mx = fmaxf(fmaxf(m0, m1), fmaxf(m2, m3));
    float e0 = __expf(m0 - mx), e1 = __expf(m1 - mx);
    float e2 = __expf(m2 - mx), e3 = __expf(m3 - mx);
    float L = pl[(bh * 4 + 0) * NU + q] * e0 + pl[(bh * 4 + 1) * NU + q] * e1 +
              pl[(bh * 4 + 2) * NU + q] * e2 + pl[(bh * 4 + 3) * NU + q] * e3;
    float o = (pacc[((size_t)(bh * 4 + 0) * NU + q) * 64 + d] * e0 +
               pacc[((size_t)(bh * 4 + 1) * NU + q) * 64 + d] * e1 +
               pacc[((size_t)(bh * 4 + 2) * NU + q) * 64 + d] * e2 +
               pacc[((size_t)(bh * 4 + 3) * NU + q) * 64 + d] * e3) / L;
    tout[((size_t)bh * NU + q) * 64 + d] = o;
  }
}

// ---------------------------------------------------------------------------
// om[b][512] = concat_h(vbar[b,h]) @ Wo + bo
// ---------------------------------------------------------------------------
__global__ void meanout(const float* __restrict__ vbarf, const float* __restrict__ Wo,
                        const float* __restrict__ bo, float* __restrict__ om) {
  int b = blockIdx.x >> 1;
  int n = (blockIdx.x & 1) * 256 + threadIdx.x;
  const float* vb = vbarf + b * 512;
  float acc = bo[n];
#pragma unroll 4
  for (int k = 0; k < 512; ++k) acc += vb[k] * Wo[(size_t)k * 512 + n];
  om[b * 512 + n] = acc;
}

// ---------------------------------------------------------------------------
// out[m][:] = om[b][:] for all 16384 rows
// ---------------------------------------------------------------------------
__global__ void fillout(const float* __restrict__ om, float* __restrict__ out) {
  const size_t n4 = (size_t)NM * 128;
  for (size_t i = (size_t)blockIdx.x * 256 + threadIdx.x; i < n4;
       i += (size_t)gridDim.x * 256) {
    int m = (int)(i >> 7), c4 = (int)(i & 127) << 2;
    int b = m >> 11;
    *(float4*)(out + (size_t)m * 512 + c4) = *(const float4*)(om + b * 512 + c4);
  }
}

// ---------------------------------------------------------------------------
// out[row(b,s)] += (tout - vbar) @ Wo[h-block]   for the 2560 selected rows
// ---------------------------------------------------------------------------
__global__ __launch_bounds__(256) void deltaout(const float* __restrict__ tout,
                                                const float* __restrict__ vbarf,
                                                const int* __restrict__ tidx,
                                                const float* __restrict__ Wo,
                                                float* __restrict__ out) {
  const int g = blockIdx.x;  // bh*40 + q
  const int bh = g / 40;
  const int b = bh >> 3, h = bh & 7;
  const int s = tidx[g];
  __shared__ float dsh[64];
  if (threadIdx.x < 64)
    dsh[threadIdx.x] = tout[(size_t)g * 64 + threadIdx.x] - vbarf[bh * 64 + threadIdx.x];
  __syncthreads();
  const int n = threadIdx.x;
  float a0 = 0.f, a1 = 0.f;
#pragma unroll 8
  for (int dh = 0; dh < 64; ++dh) {
    float d = dsh[dh];
    const float* wrow = Wo + (size_t)(h * 64 + dh) * 512;
    a0 = fmaf(d, wrow[n], a0);
    a1 = fmaf(d, wrow[n + 256], a1);
  }
  float* orow = out + ((size_t)b * 2048 + s) * 512;
  atomicAdd(orow + n, a0);
  atomicAdd(orow + n + 256, a1);
}

// ---------------------------------------------------------------------------
extern "C" void kernel_launch(void* const* d_in, const int* in_sizes, int n_in,
                              void* d_out, int out_size, void* d_ws, size_t ws_size,
                              hipStream_t stream) {
  (void)in_sizes; (void)n_in; (void)out_size; (void)ws_size;
  const float* x  = (const float*)d_in[0];
  const float* wq = (const float*)d_in[1];
  const float* bq = (const float*)d_in[2];
  const float* wk = (const float*)d_in[3];
  const float* bk = (const float*)d_in[4];
  const float* wv = (const float*)d_in[5];
  const float* bv = (const float*)d_in[6];
  const float* wo = (const float*)d_in[7];
  const float* bo = (const float*)d_in[8];
  float* out = (float*)d_out;

  short* Xs   = (short*)d_ws;                              // 16384*1024
  short* Wts  = Xs + (size_t)16384 * 1024;                 // 3*512*1024
  short* Qsb  = Wts + (size_t)3 * 512 * 1024;              // 64*2048*128 each
  short* Ksb  = Qsb + (size_t)NBH * NS * 128;
  short* Vsb  = Ksb + (size_t)NBH * NS * 128;
  float* Mval = (float*)(Vsb + (size_t)NBH * NS * 128);    // 131072
  float* kbarf = Mval + (size_t)NBH * NS;                  // 4096
  float* vbarf = kbarf + NBH * 64;                         // 4096
  int* tidx   = (int*)(vbarf + NBH * 64);                  // 2560
  float* pacc = (float*)(tidx + NBH * NU);                 // 64*4*40*64
  float* pm   = pacc + (size_t)NBH * 4 * NU * 64;          // 10240
  float* pl   = pm + NBH * 4 * NU;                         // 10240
  float* tout = pl + NBH * 4 * NU;                         // 64*40*64
  float* om   = tout + (size_t)NBH * NU * 64;              // 4096

  splitx<<<8192, 256, 0, stream>>>(x, Xs);
  wsplit<<<dim3(256, 3), 256, 0, stream>>>(wq, wk, wv, Wts);
  qkvgemm<<<1536, 256, 0, stream>>>(Xs, Wts, bq, bk, bv, Qsb, Ksb, Vsb);
  colmeans<<<NBH, 256, 0, stream>>>(Ksb, Vsb, kbarf, vbarf);
  qkmax<<<512, 256, 0, stream>>>(Qsb, Ksb, kbarf, Mval);
  topk40<<<NBH, 256, 0, stream>>>(Mval, tidx);
  topattn1<<<dim3(NBH, 4), 256, 0, stream>>>(Qsb, Ksb, Vsb, tidx, pacc, pm, pl);
  topcombine<<<NBH, 256, 0, stream>>>(pacc, pm, pl, tout);
  meanout<<<16, 256, 0, stream>>>(vbarf, wo, bo, om);
  fillout<<<2048, 256, 0, stream>>>(om, out);
  deltaout<<<NBH * NU, 256, 0, stream>>>(tout, vbarf, tidx, wo, out);
}

// Round 4
// 338.421 us; speedup vs baseline: 3.7900x; 1.2947x over previous
//
#include <hip/hip_runtime.h>
#include <hip/hip_bf16.h>
#include <math.h>

// B=8, S=2048, D=512, H=8, Dh=64, u = 5*ceil(ln(2048)) = 40
#define NB 8
#define NS 2048
#define ND 512
#define NH 8
#define DHD 64
#define NU 40
#define NBH 64
#define NM 16384  // NB*NS

typedef __attribute__((ext_vector_type(8))) short short8;
typedef __attribute__((ext_vector_type(4))) short short4v;
typedef __attribute__((ext_vector_type(4))) float f32x4;

__device__ __forceinline__ short f2bf(float f) {
  __hip_bfloat16 h = __float2bfloat16(f);
  return *reinterpret_cast<short*>(&h);
}
__device__ __forceinline__ float bf2f(short s) {
  __hip_bfloat16 h;
  *reinterpret_cast<short*>(&h) = s;
  return __bfloat162float(h);
}

// async global->LDS, 16B per lane; LDS dest = wave-uniform base + lane*16
__device__ __forceinline__ void gload_lds16(const short* g, short* l) {
  __builtin_amdgcn_global_load_lds(
      (const __attribute__((address_space(1))) unsigned int*)g,
      (__attribute__((address_space(3))) unsigned int*)l, 16, 0, 0);
}

// ---------------------------------------------------------------------------
// Fused prep: blocks 0..8191 split x; blocks 8192..8959 split+transpose W q/k/v
// ---------------------------------------------------------------------------
__global__ void prep(const float* __restrict__ x, const float* __restrict__ w0,
                     const float* __restrict__ w1, const float* __restrict__ w2,
                     short* __restrict__ Xs, short* __restrict__ Wts) {
  if (blockIdx.x < 8192) {
    int i = blockIdx.x * 256 + threadIdx.x;  // chunk of 4 floats
    const float4 v = *(const float4*)(x + (size_t)i * 4);
    int row = i >> 7;
    int col = (i & 127) << 2;
    float vv[4] = {v.x, v.y, v.z, v.w};
    short4v hi, lo;
#pragma unroll
    for (int j = 0; j < 4; ++j) {
      short h = f2bf(vv[j]);
      hi[j] = h;
      lo[j] = f2bf(vv[j] - bf2f(h));
    }
    *(short4v*)(Xs + (size_t)row * 1024 + col) = hi;
    *(short4v*)(Xs + (size_t)row * 1024 + 512 + col) = lo;
  } else {
    int bw = blockIdx.x - 8192;
    int y = bw >> 8;           // 0..2 -> wq,wk,wv
    int bxy = bw & 255;
    const float* W = y == 0 ? w0 : y == 1 ? w1 : w2;
    short* dst = Wts + (size_t)y * 512 * 1024;
    __shared__ float tile[32][33];
    int bx = bxy & 15, by = bxy >> 4;
    int k0 = bx * 32, n0 = by * 32;
    int r = threadIdx.x >> 3, cg = (threadIdx.x & 7) * 4;
    const float4 v = *(const float4*)(W + (size_t)(k0 + r) * 512 + n0 + cg);
    tile[r][cg] = v.x; tile[r][cg + 1] = v.y; tile[r][cg + 2] = v.z; tile[r][cg + 3] = v.w;
    __syncthreads();
#pragma unroll
    for (int j = 0; j < 4; ++j) {
      int kk = cg + j;
      float f = tile[kk][r];
      short h = f2bf(f);
      dst[(size_t)(n0 + r) * 1024 + k0 + kk] = h;
      dst[(size_t)(n0 + r) * 1024 + 512 + k0 + kk] = f2bf(f - bf2f(h));
    }
  }
}

// ---------------------------------------------------------------------------
// Split-bf16 MFMA GEMM (QKV fused): C = X(hi+lo) @ W(hi+lo) + bias
// BM=BN=128, BK=32(real), 4 waves (2x2 of 64x64). Dbuf LDS via global_load_lds.
// Swapped-operand MFMA: D row = feature(n), col = x-row(m) -> packed 8B stores.
// ---------------------------------------------------------------------------
__global__ __launch_bounds__(256, 2) void qkvgemm(
    const short* __restrict__ A, const short* __restrict__ Wts,
    const float* __restrict__ bq, const float* __restrict__ bk,
    const float* __restrict__ bv, short* __restrict__ Qs,
    short* __restrict__ Ks, short* __restrict__ Vs) {
  __shared__ short As[2][128][64];
  __shared__ short Bs[2][128][64];
  const int bid = blockIdx.x;
  const int wgid = (bid & 7) * 192 + (bid >> 3);  // 1536 = 8*192 exact
  const int mb = wgid / 12, y = wgid % 12;
  const int m0 = mb * 128;
  const int wsel = y >> 2;
  const int n0 = (y & 3) * 128;
  const short* Wb = Wts + (size_t)wsel * 512 * 1024;
  const float* bias = wsel == 0 ? bq : wsel == 1 ? bk : bv;
  short* dstbase = wsel == 0 ? Qs : wsel == 1 ? Ks : Vs;

  const int tid = threadIdx.x;
  const int w = tid >> 6, lane = tid & 63;
  const int wm = (w >> 1) * 64, wn = (w & 1) * 64;
  const int fr = lane & 15, fk = lane >> 4;

  f32x4 acc[4][4];
  const f32x4 zz = {0.f, 0.f, 0.f, 0.f};
#pragma unroll
  for (int i = 0; i < 4; ++i)
#pragma unroll
    for (int j = 0; j < 4; ++j) acc[i][j] = zz;

  auto stage = [&](int buf, int kt) {
#pragma unroll
    for (int p = 0; p < 4; ++p) {
      int idx = (p * 4 + w) * 64 + lane;   // 0..1023
      int r = idx >> 3, c = idx & 7;
      int cs = c ^ (r & 7);                // inverse-swizzled source chunk
      int sc = (cs < 4) ? (kt + cs * 8) : (512 + kt + (cs - 4) * 8);
      short* lA = &As[buf][0][0] + (p * 4 + w) * 512;
      short* lB = &Bs[buf][0][0] + (p * 4 + w) * 512;
      gload_lds16(A + (size_t)(m0 + r) * 1024 + sc, lA);
      gload_lds16(Wb + (size_t)(n0 + r) * 1024 + sc, lB);
    }
  };

  stage(0, 0);
  __syncthreads();
  for (int kt = 0; kt < 512; kt += 32) {
    int cur = (kt >> 5) & 1;
    if (kt + 32 < 512) stage(cur ^ 1, kt + 32);
    short8 ah[4], al[4], bh[4], bl[4];
#pragma unroll
    for (int mf = 0; mf < 4; ++mf) {
      int r = wm + mf * 16 + fr;
      ah[mf] = *(const short8*)&As[cur][r][(fk ^ (r & 7)) << 3];
      al[mf] = *(const short8*)&As[cur][r][((4 + fk) ^ (r & 7)) << 3];
    }
#pragma unroll
    for (int nf = 0; nf < 4; ++nf) {
      int r = wn + nf * 16 + fr;
      bh[nf] = *(const short8*)&Bs[cur][r][(fk ^ (r & 7)) << 3];
      bl[nf] = *(const short8*)&Bs[cur][r][((4 + fk) ^ (r & 7)) << 3];
    }
#pragma unroll
    for (int mf = 0; mf < 4; ++mf)
#pragma unroll
      for (int nf = 0; nf < 4; ++nf) {
        acc[mf][nf] = __builtin_amdgcn_mfma_f32_16x16x32_bf16(bh[nf], ah[mf], acc[mf][nf], 0, 0, 0);
        acc[mf][nf] = __builtin_amdgcn_mfma_f32_16x16x32_bf16(bh[nf], al[mf], acc[mf][nf], 0, 0, 0);
        acc[mf][nf] = __builtin_amdgcn_mfma_f32_16x16x32_bf16(bl[nf], ah[mf], acc[mf][nf], 0, 0, 0);
      }
    __syncthreads();
  }

#pragma unroll
  for (int mf = 0; mf < 4; ++mf) {
    int m = m0 + wm + mf * 16 + fr;
    int b = m >> 11, s = m & 2047;
#pragma unroll
    for (int nf = 0; nf < 4; ++nf) {
      int nb = n0 + wn + nf * 16 + fk * 4;
      float4 bi4 = *(const float4*)(bias + nb);
      int h = nb >> 6, dh = nb & 63;
      short* dst = dstbase + ((size_t)((b << 3) + h) * 2048 + s) * 128;
      short4v hi, lo;
      float bb[4] = {bi4.x, bi4.y, bi4.z, bi4.w};
#pragma unroll
      for (int j = 0; j < 4; ++j) {
        float v = acc[mf][nf][j] + bb[j];
        short hs = f2bf(v);
        hi[j] = hs;
        lo[j] = f2bf(v - bf2f(hs));
      }
      *(short4v*)(dst + dh) = hi;
      *(short4v*)(dst + 64 + dh) = lo;
    }
  }
}

// ---------------------------------------------------------------------------
// Column means of K and V (hi+lo): 4 blocks per bh, pre-scaled atomic partials
// into kbarf/vbarf (zeroed by memset beforehand).
// ---------------------------------------------------------------------------
__global__ __launch_bounds__(256) void colmeans(const short* __restrict__ K,
                                                const short* __restrict__ V,
                                                float* __restrict__ kbarf,
                                                float* __restrict__ vbarf) {
  const int bh = blockIdx.x >> 2, part = blockIdx.x & 3;
  const int c = threadIdx.x & 15;   // 8-short column chunk
  const int g = threadIdx.x >> 4;   // row group (16 groups of 32 rows)
  const int s0 = part * 512 + g * 32;
  const short* Kb = K + (size_t)bh * 2048 * 128;
  const short* Vb = V + (size_t)bh * 2048 * 128;
  float sk[8], sv[8];
#pragma unroll
  for (int e = 0; e < 8; ++e) { sk[e] = 0.f; sv[e] = 0.f; }
  for (int s = s0; s < s0 + 32; ++s) {
    short8 k8 = *(const short8*)(Kb + (size_t)s * 128 + c * 8);
    short8 v8 = *(const short8*)(Vb + (size_t)s * 128 + c * 8);
#pragma unroll
    for (int e = 0; e < 8; ++e) { sk[e] += bf2f(k8[e]); sv[e] += bf2f(v8[e]); }
  }
  __shared__ float rk[16][128], rv[16][128];
#pragma unroll
  for (int e = 0; e < 8; ++e) { rk[g][c * 8 + e] = sk[e]; rv[g][c * 8 + e] = sv[e]; }
  __syncthreads();
  if (threadIdx.x < 64) {
    int d = threadIdx.x;
    float a = 0.f, b2 = 0.f;
    for (int g2 = 0; g2 < 16; ++g2) {
      a += rk[g2][d] + rk[g2][64 + d];
      b2 += rv[g2][d] + rv[g2][64 + d];
    }
    atomicAdd(kbarf + bh * 64 + d, a * (1.f / 2048.f));
    atomicAdd(vbarf + bh * 64 + d, b2 * (1.f / 2048.f));
  }
}

// ---------------------------------------------------------------------------
// QK^T row-max via split-bf16 MFMA + fused M = (max - q.kbar)/8.
// ---------------------------------------------------------------------------
__global__ __launch_bounds__(256, 2) void qkmax(const short* __restrict__ Qs,
                                                const short* __restrict__ Ks,
                                                const float* __restrict__ kbarf,
                                                float* __restrict__ Mval) {
  __shared__ short Kt[2][128][128];
  __shared__ float red[256];
  const int bid = blockIdx.x;
  const int wgid = (bid & 7) * 64 + (bid >> 3);  // 512 = 8*64 exact
  const int bh = wgid >> 3, q0 = (wgid & 7) * 256;
  const short* Qb = Qs + ((size_t)bh * 2048 + q0) * 128;
  const short* Kb = Ks + (size_t)bh * 2048 * 128;
  const int tid = threadIdx.x, w = tid >> 6, lane = tid & 63;
  const int fr = lane & 15, fk = lane >> 4;

  short8 qf[4][2][2];  // [mf][hi/lo][k0]
#pragma unroll
  for (int mf = 0; mf < 4; ++mf) {
    int row = w * 64 + mf * 16 + fr;
#pragma unroll
    for (int h = 0; h < 2; ++h)
#pragma unroll
      for (int k0 = 0; k0 < 2; ++k0) {
        int ch = h * 8 + k0 * 4 + fk;
        qf[mf][h][k0] = *(const short8*)(Qb + (size_t)row * 128 + ch * 8);
      }
  }

  f32x4 rmax[4];
  const f32x4 neg = {-1e30f, -1e30f, -1e30f, -1e30f};
#pragma unroll
  for (int mf = 0; mf < 4; ++mf) rmax[mf] = neg;
  const f32x4 zz = {0.f, 0.f, 0.f, 0.f};

  auto stageK = [&](int buf, int t) {
#pragma unroll
    for (int p = 0; p < 8; ++p) {
      int idx = (p * 4 + w) * 64 + lane;  // 0..2047
      int r = idx >> 4, c = idx & 15;
      int cs = c ^ (r & 15);
      short* lb = &Kt[buf][0][0] + (p * 4 + w) * 512;
      gload_lds16(Kb + (size_t)(t * 128 + r) * 128 + cs * 8, lb);
    }
  };

  stageK(0, 0);
  __syncthreads();
  for (int t = 0; t < 16; ++t) {
    int cur = t & 1;
    if (t < 15) stageK(cur ^ 1, t + 1);
#pragma unroll
    for (int nf = 0; nf < 8; ++nf) {
      int r = nf * 16 + fr;
      short8 kfh[2], kfl[2];
#pragma unroll
      for (int k0 = 0; k0 < 2; ++k0) {
        kfh[k0] = *(const short8*)&Kt[cur][r][((k0 * 4 + fk) ^ (r & 15)) << 3];
        kfl[k0] = *(const short8*)&Kt[cur][r][((8 + k0 * 4 + fk) ^ (r & 15)) << 3];
      }
#pragma unroll
      for (int mf = 0; mf < 4; ++mf) {
        f32x4 a = zz;
#pragma unroll
        for (int k0 = 0; k0 < 2; ++k0) {
          a = __builtin_amdgcn_mfma_f32_16x16x32_bf16(qf[mf][0][k0], kfh[k0], a, 0, 0, 0);
          a = __builtin_amdgcn_mfma_f32_16x16x32_bf16(qf[mf][0][k0], kfl[k0], a, 0, 0, 0);
          a = __builtin_amdgcn_mfma_f32_16x16x32_bf16(qf[mf][1][k0], kfh[k0], a, 0, 0, 0);
        }
#pragma unroll
        for (int j = 0; j < 4; ++j) rmax[mf][j] = fmaxf(rmax[mf][j], a[j]);
      }
    }
    __syncthreads();
  }

#pragma unroll
  for (int mf = 0; mf < 4; ++mf)
#pragma unroll
    for (int j = 0; j < 4; ++j) {
      float r = rmax[mf][j];
      r = fmaxf(r, __shfl_xor(r, 1, 64));
      r = fmaxf(r, __shfl_xor(r, 2, 64));
      r = fmaxf(r, __shfl_xor(r, 4, 64));
      r = fmaxf(r, __shfl_xor(r, 8, 64));
      if (fr == 0) red[w * 64 + mf * 16 + fk * 4 + j] = r;
    }
  __syncthreads();

  {
    const short* qp = Qs + ((size_t)bh * 2048 + q0 + tid) * 128;
    const float* kb = kbarf + bh * 64;
    float dot = 0.f;
#pragma unroll
    for (int ch = 0; ch < 8; ++ch) {
      short8 hi = *(const short8*)(qp + ch * 8);
      short8 lo = *(const short8*)(qp + 64 + ch * 8);
#pragma unroll
      for (int e = 0; e < 8; ++e) dot += (bf2f(hi[e]) + bf2f(lo[e])) * kb[ch * 8 + e];
    }
    Mval[(size_t)bh * 2048 + q0 + tid] = (red[tid] - dot) * 0.125f;
  }
}

// ---------------------------------------------------------------------------
// top-40 per (bh): one WAVE per bh, no __syncthreads. Lane-private LDS slices,
// 6-step shfl butterfly argmax with tie -> lower index.
// Grid 16 blocks x 256 threads (4 waves, wave w handles bh = blk*4+w).
// ---------------------------------------------------------------------------
__global__ __launch_bounds__(256) void topk40(const float* __restrict__ Mval,
                                              int* __restrict__ tidx) {
  __shared__ float vals[4][32][64];
  const int w = threadIdx.x >> 6, lane = threadIdx.x & 63;
  const int bh = blockIdx.x * 4 + w;
  const float* src = Mval + (size_t)bh * 2048;
#pragma unroll
  for (int j = 0; j < 32; ++j) vals[w][j][lane] = src[j * 64 + lane];

  for (int it = 0; it < NU; ++it) {
    float best = -INFINITY;
    int bi = 1 << 30;
#pragma unroll
    for (int j = 0; j < 32; ++j) {
      float x = vals[w][j][lane];
      int idx = j * 64 + lane;
      if (x > best) { best = x; bi = idx; }   // lane's own idx increases with j
    }
#pragma unroll
    for (int off = 1; off < 64; off <<= 1) {
      float ov = __shfl_xor(best, off, 64);
      int oi = __shfl_xor(bi, off, 64);
      if (ov > best || (ov == best && oi < bi)) { best = ov; bi = oi; }
    }
    if (lane == 0) tidx[bh * NU + it] = bi;
    if ((bi & 63) == lane) vals[w][bi >> 6][lane] = -INFINITY;
  }
}

// ---------------------------------------------------------------------------
// Dense attention for 40 selected queries, key-split over 4 chunks (partials)
// ---------------------------------------------------------------------------
__global__ __launch_bounds__(256) void topattn1(const short* __restrict__ Qs,
                                                const short* __restrict__ Ks,
                                                const short* __restrict__ Vs,
                                                const int* __restrict__ topidx,
                                                float* __restrict__ pacc,
                                                float* __restrict__ pm,
                                                float* __restrict__ pl) {
  __shared__ float qs[40][68];
  __shared__ float Kst[64][132];
  __shared__ float Vsh[128][68];
  __shared__ float st[40][132];
  __shared__ float m_s[40], l_s[40], r_s[40];
  __shared__ int tix[40];
  const int tid = threadIdx.x;
  const int bh = blockIdx.x, kc = blockIdx.y;
  const short* Kb = Ks + (size_t)bh * 2048 * 128;
  const short* Vb = Vs + (size_t)bh * 2048 * 128;

  if (tid < 40) {
    tix[tid] = topidx[bh * NU + tid];
    m_s[tid] = -INFINITY;
    l_s[tid] = 0.f;
  }
  __syncthreads();
  for (int i = tid; i < 40 * 64; i += 256) {
    int q = i >> 6, dd2 = i & 63;
    const short* qp = Qs + ((size_t)bh * 2048 + tix[q]) * 128;
    qs[q][dd2] = bf2f(qp[dd2]) + bf2f(qp[64 + dd2]);
  }
  const int tx = tid & 31, ty = tid >> 5;
  const int d = tid & 63, qb = tid >> 6;
  float acc[10];
#pragma unroll
  for (int j = 0; j < 10; ++j) acc[j] = 0.f;
  __syncthreads();

  for (int t = 0; t < 4; ++t) {
    int krow0 = kc * 512 + t * 128;
#pragma unroll
    for (int p = 0; p < 4; ++p) {
      int idx = tid + (p << 8);
      int r = idx >> 3, cg = (idx & 7) << 3;
      const short8 kh = *(const short8*)(Kb + (size_t)(krow0 + r) * 128 + cg);
      const short8 kl = *(const short8*)(Kb + (size_t)(krow0 + r) * 128 + 64 + cg);
      const short8 vh = *(const short8*)(Vb + (size_t)(krow0 + r) * 128 + cg);
      const short8 vl = *(const short8*)(Vb + (size_t)(krow0 + r) * 128 + 64 + cg);
#pragma unroll
      for (int j = 0; j < 8; ++j) {
        Kst[cg + j][r] = bf2f(kh[j]) + bf2f(kl[j]);
        Vsh[r][cg + j] = bf2f(vh[j]) + bf2f(vl[j]);
      }
    }
    __syncthreads();

    {
      float c5[5][4];
#pragma unroll
      for (int i = 0; i < 5; ++i)
#pragma unroll
        for (int j = 0; j < 4; ++j) c5[i][j] = 0.f;
      for (int dd = 0; dd < 64; ++dd) {
        const float4 b4 = *(const float4*)&Kst[dd][tx << 2];
#pragma unroll
        for (int i = 0; i < 5; ++i) {
          float a = qs[ty * 5 + i][dd];
          c5[i][0] = fmaf(a, b4.x, c5[i][0]);
          c5[i][1] = fmaf(a, b4.y, c5[i][1]);
          c5[i][2] = fmaf(a, b4.z, c5[i][2]);
          c5[i][3] = fmaf(a, b4.w, c5[i][3]);
        }
      }
#pragma unroll
      for (int i = 0; i < 5; ++i) {
        float4 o;
        o.x = c5[i][0] * 0.125f; o.y = c5[i][1] * 0.125f;
        o.z = c5[i][2] * 0.125f; o.w = c5[i][3] * 0.125f;
        *(float4*)&st[ty * 5 + i][tx << 2] = o;
      }
    }
    __syncthreads();

    // wave-parallel online softmax: 4 lanes per query
    if (tid < 160) {
      int q = tid >> 2, sub = tid & 3;
      float tm = -INFINITY;
#pragma unroll
      for (int kk = 0; kk < 32; ++kk) tm = fmaxf(tm, st[q][sub * 32 + kk]);
      tm = fmaxf(tm, __shfl_xor(tm, 1, 64));
      tm = fmaxf(tm, __shfl_xor(tm, 2, 64));
      float mold = m_s[q];
      float mnew = fmaxf(mold, tm);
      float sum = 0.f;
#pragma unroll
      for (int kk = 0; kk < 32; ++kk) {
        float ww = __expf(st[q][sub * 32 + kk] - mnew);
        st[q][sub * 32 + kk] = ww;
        sum += ww;
      }
      sum += __shfl_xor(sum, 1, 64);
      sum += __shfl_xor(sum, 2, 64);
      if (sub == 0) {
        float r = __expf(mold - mnew);
        l_s[q] = l_s[q] * r + sum;
        m_s[q] = mnew;
        r_s[q] = r;
      }
    }
    __syncthreads();

#pragma unroll
    for (int j = 0; j < 10; ++j) {
      int q = qb + (j << 2);
      float a = 0.f;
#pragma unroll
      for (int kk = 0; kk < 128; kk += 4) {
        float4 ww = *(const float4*)&st[q][kk];
        a = fmaf(ww.x, Vsh[kk + 0][d], a);
        a = fmaf(ww.y, Vsh[kk + 1][d], a);
        a = fmaf(ww.z, Vsh[kk + 2][d], a);
        a = fmaf(ww.w, Vsh[kk + 3][d], a);
      }
      acc[j] = acc[j] * r_s[q] + a;
    }
    __syncthreads();
  }

  int pcb = bh * 4 + kc;
#pragma unroll
  for (int j = 0; j < 10; ++j) {
    int q = qb + (j << 2);
    pacc[((size_t)pcb * NU + q) * 64 + d] = acc[j];
  }
  if (tid < 40) {
    pm[pcb * NU + tid] = m_s[tid];
    pl[pcb * NU + tid] = l_s[tid];
  }
}

// ---------------------------------------------------------------------------
// Blocks 0..63: combine 4 key-chunk partials -> tout[bh][40][64] f32
// Blocks 64..127: om[b][512] = concat_h(vbar[b,h]) @ Wo + bo   (k-split x4)
// ---------------------------------------------------------------------------
__global__ __launch_bounds__(256) void topcombine(const float* __restrict__ pacc,
                                                  const float* __restrict__ pm,
                                                  const float* __restrict__ pl,
                                                  float* __restrict__ tout,
                                                  const float* __restrict__ vbarf,
                                                  const float* __restrict__ Wo,
                                                  const float* __restrict__ bo,
                                                  float* __restrict__ om) {
  if (blockIdx.x < 64) {
    const int bh = blockIdx.x;
    const int d = threadIdx.x & 63, qb = threadIdx.x >> 6;
#pragma unroll
    for (int j = 0; j < 10; ++j) {
      int q = qb + (j << 2);
      float m0 = pm[(bh * 4 + 0) * NU + q], m1 = pm[(bh * 4 + 1) * NU + q];
      float m2 = pm[(bh * 4 + 2) * NU + q], m3 = pm[(bh * 4 + 3) * NU + q];
      float mx = fmaxf(fmaxf(m0, m1), fmaxf(m2, m3));
      float e0 = __expf(m0 - mx), e1 = __expf(m1 - mx);
      float e2 = __expf(m2 - mx), e3 = __expf(m3 - mx);
      float L = pl[(bh * 4 + 0) * NU + q] * e0 + pl[(bh * 4 + 1) * NU + q] * e1 +
                pl[(bh * 4 + 2) * NU + q] * e2 + pl[(bh * 4 + 3) * NU + q] * e3;
      float o = (pacc[((size_t)(bh * 4 + 0) * NU + q) * 64 + d] * e0 +
                 pacc[((size_t)(bh * 4 + 1) * NU + q) * 64 + d] * e1 +
                 pacc[((size_t)(bh * 4 + 2) * NU + q) * 64 + d] * e2 +
                 pacc[((size_t)(bh * 4 + 3) * NU + q) * 64 + d] * e3) / L;
      tout[((size_t)bh * NU + q) * 64 + d] = o;
    }
  } else {
    __shared__ float mred[4][64];
    int blk2 = blockIdx.x - 64;          // 0..63
    int b = blk2 >> 3, n0 = (blk2 & 7) * 64;
    int n = n0 + (threadIdx.x & 63), kq = threadIdx.x >> 6;
    const float* vb = vbarf + b * 512;
    float acc = 0.f;
#pragma unroll 8
    for (int k = kq * 128; k < kq * 128 + 128; ++k)
      acc = fmaf(vb[k], Wo[(size_t)k * 512 + n], acc);
    mred[kq][threadIdx.x & 63] = acc;
    __syncthreads();
    if (kq == 0)
      om[b * 512 + n] = bo[n] + mred[0][n - n0] + mred[1][n - n0] +
                        mred[2][n - n0] + mred[3][n - n0];
  }
}

// ---------------------------------------------------------------------------
// out[m][:] = om[b][:] for all 16384 rows
// ---------------------------------------------------------------------------
__global__ void fillout(const float* __restrict__ om, float* __restrict__ out) {
  const size_t n4 = (size_t)NM * 128;
  for (size_t i = (size_t)blockIdx.x * 256 + threadIdx.x; i < n4;
       i += (size_t)gridDim.x * 256) {
    int m = (int)(i >> 7), c4 = (int)(i & 127) << 2;
    int b = m >> 11;
    *(float4*)(out + (size_t)m * 512 + c4) = *(const float4*)(om + b * 512 + c4);
  }
}

// ---------------------------------------------------------------------------
// out[row(b,s)] += (tout - vbar) @ Wo[h-block]   for the 2560 selected rows
// ---------------------------------------------------------------------------
__global__ __launch_bounds__(256) void deltaout(const float* __restrict__ tout,
                                                const float* __restrict__ vbarf,
                                                const int* __restrict__ tidx,
                                                const float* __restrict__ Wo,
                                                float* __restrict__ out) {
  const int g = blockIdx.x;  // bh*40 + q
  const int bh = g / 40;
  const int b = bh >> 3, h = bh & 7;
  const int s = tidx[g];
  __shared__ float dsh[64];
  if (threadIdx.x < 64)
    dsh[threadIdx.x] = tout[(size_t)g * 64 + threadIdx.x] - vbarf[bh * 64 + threadIdx.x];
  __syncthreads();
  const int n = threadIdx.x;
  float a0 = 0.f, a1 = 0.f;
#pragma unroll 8
  for (int dh = 0; dh < 64; ++dh) {
    float d = dsh[dh];
    const float* wrow = Wo + (size_t)(h * 64 + dh) * 512;
    a0 = fmaf(d, wrow[n], a0);
    a1 = fmaf(d, wrow[n + 256], a1);
  }
  float* orow = out + ((size_t)b * 2048 + s) * 512;
  atomicAdd(orow + n, a0);
  atomicAdd(orow + n + 256, a1);
}

// ---------------------------------------------------------------------------
extern "C" void kernel_launch(void* const* d_in, const int* in_sizes, int n_in,
                              void* d_out, int out_size, void* d_ws, size_t ws_size,
                              hipStream_t stream) {
  (void)in_sizes; (void)n_in; (void)out_size; (void)ws_size;
  const float* x  = (const float*)d_in[0];
  const float* wq = (const float*)d_in[1];
  const float* bq = (const float*)d_in[2];
  const float* wk = (const float*)d_in[3];
  const float* bk = (const float*)d_in[4];
  const float* wv = (const float*)d_in[5];
  const float* bv = (const float*)d_in[6];
  const float* wo = (const float*)d_in[7];
  const float* bo = (const float*)d_in[8];
  float* out = (float*)d_out;

  short* Xs   = (short*)d_ws;                              // 16384*1024
  short* Wts  = Xs + (size_t)16384 * 1024;                 // 3*512*1024
  short* Qsb  = Wts + (size_t)3 * 512 * 1024;              // 64*2048*128 each
  short* Ksb  = Qsb + (size_t)NBH * NS * 128;
  short* Vsb  = Ksb + (size_t)NBH * NS * 128;
  float* Mval = (float*)(Vsb + (size_t)NBH * NS * 128);    // 131072
  float* kbarf = Mval + (size_t)NBH * NS;                  // 4096
  float* vbarf = kbarf + NBH * 64;                         // 4096
  int* tidx   = (int*)(vbarf + NBH * 64);                  // 2560
  float* pacc = (float*)(tidx + NBH * NU);                 // 64*4*40*64
  float* pm   = pacc + (size_t)NBH * 4 * NU * 64;          // 10240
  float* pl   = pm + NBH * 4 * NU;                         // 10240
  float* tout = pl + NBH * 4 * NU;                         // 64*40*64
  float* om   = tout + (size_t)NBH * NU * 64;              // 4096

  hipMemsetAsync(kbarf, 0, 2 * NBH * 64 * sizeof(float), stream);
  prep<<<8960, 256, 0, stream>>>(x, wq, wk, wv, Xs, Wts);
  qkvgemm<<<1536, 256, 0, stream>>>(Xs, Wts, bq, bk, bv, Qsb, Ksb, Vsb);
  colmeans<<<NBH * 4, 256, 0, stream>>>(Ksb, Vsb, kbarf, vbarf);
  qkmax<<<512, 256, 0, stream>>>(Qsb, Ksb, kbarf, Mval);
  topk40<<<16, 256, 0, stream>>>(Mval, tidx);
  topattn1<<<dim3(NBH, 4), 256, 0, stream>>>(Qsb, Ksb, Vsb, tidx, pacc, pm, pl);
  topcombine<<<128, 256, 0, stream>>>(pacc, pm, pl, tout, vbarf, wo, bo, om);
  fillout<<<2048, 256, 0, stream>>>(om, out);
  deltaout<<<NBH * NU, 256, 0, stream>>>(tout, vbarf, tidx, wo, out);
}